// Round 5
// baseline (737.252 us; speedup 1.0000x reference)
//
#include <hip/hip_runtime.h>

#define B_ 64
#define T_ 2048
#define LD_ 16
#define HD_ 64
#define K_ 8
#define L_ 16
#define C_ 128

// ---------------- workspace layout (floats) ----------------
constexpr int OFF_LE    = 0;                    // T*B*K
constexpr int OFF_ALPHA = 1048576;              // T*B*K
constexpr int OFF_EBAR  = 2097152;              // T*B*K
constexpr int OFF_PBUF  = 3145728;              // C*B*64 = 524288 (fwd P; rbuf aliases after fwdP2)
constexpr int OFF_RLOG  = 3670016;              // C*B = 8192
constexpr int OFF_AIN   = 3678208;              // C*B*K = 65536
constexpr int OFF_SB    = 3743744;              // C*B*K = 65536
constexpr int OFF_PRM   = 3809280;              // params (~4.3K floats); total ~15.3 MB

// params region (relative to OFF_PRM), float-indexed
constexpr int P_LINV0 = 0;       // 8*16*16
constexpr int P_LINVT = 2048;    // 8*16*16
constexpr int P_LD0   = 4096;    // 8
constexpr int P_LDT   = 4104;    // 8
constexpr int P_LOGPI = 4112;    // 8
constexpr int P_QEXP  = 4120;    // 64
constexpr int P_QTEXP = 4184;    // 64

// output layout (floats)
constexpr int OUT_PAIRED = B_*T_*K_;                       // 1048576
constexpr int OUT_LOGZ   = OUT_PAIRED + B_*(T_-1)*K_*K_;   // 9433088

// ---------------- DPP helpers (aligned groups of 8 lanes) ----------------
template<int CTRL>
__device__ __forceinline__ float dppmov(float x) {
  int xi = __float_as_int(x);
  int r = __builtin_amdgcn_update_dpp(xi, xi, CTRL, 0xF, 0xF, true);
  return __int_as_float(r);
}
// 0xB1=xor1, 0x4E=xor2, 0x141=row_half_mirror=xor7 (within 8)
__device__ __forceinline__ void allg8(float v, float w[8]) {
  w[0] = v;
  w[1] = dppmov<0xB1>(v);
  w[2] = dppmov<0x4E>(v);
  w[3] = dppmov<0x4E>(w[1]);
  w[7] = dppmov<0x141>(v);
  w[6] = dppmov<0xB1>(w[7]);
  w[5] = dppmov<0x4E>(w[7]);
  w[4] = dppmov<0x4E>(w[6]);
}
__device__ __forceinline__ float bfly_sum8(float x) {
  x += dppmov<0xB1>(x); x += dppmov<0x4E>(x); x += dppmov<0x141>(x); return x;
}
__device__ __forceinline__ float bfly_max8(float x) {
  x = fmaxf(x, dppmov<0xB1>(x)); x = fmaxf(x, dppmov<0x4E>(x)); x = fmaxf(x, dppmov<0x141>(x)); return x;
}
__device__ __forceinline__ float rcpnr(float x) {
  float r0 = __builtin_amdgcn_rcpf(x);
  return r0 * __builtin_fmaf(-x, r0, 2.0f);
}

// ---------------- kernel 1: Cholesky / softmax params ----------------
__global__ __launch_bounds__(64) void prep_kernel(
    const float* __restrict__ pi, const float* __restrict__ Q,
    const float* __restrict__ init_cov, const float* __restrict__ covs,
    float* __restrict__ prm)
{
  int tid = threadIdx.x;
  int blk = blockIdx.x;
  if (blk < 16) {
    int k = blk & 7;
    const float* C = (blk < 8 ? init_cov : covs) + k*256;
    float* outL  = prm + (blk < 8 ? P_LINV0 : P_LINVT) + k*256;
    float* outld = prm + (blk < 8 ? P_LD0   : P_LDT)   + k;
    __shared__ float S[16][17], L[16][17], X[16][17];
    for (int e = tid; e < 256; e += 64) {
      int r = e >> 4, c = e & 15;
      float s = (r == c) ? 1e-6f : 0.f;
      for (int l = 0; l < 16; l++) s += C[r*16+l] * C[c*16+l];
      S[r][c] = s;
    }
    __syncthreads();
    for (int j = 0; j < 16; j++) {
      if (tid == 0) L[j][j] = sqrtf(S[j][j]);
      __syncthreads();
      if (tid > j && tid < 16) L[tid][j] = S[tid][j] / L[j][j];
      __syncthreads();
      if (tid > j && tid < 16) {
        float ltj = L[tid][j];
        for (int c = j+1; c <= tid; c++) S[tid][c] -= ltj * L[c][j];
      }
      __syncthreads();
    }
    if (tid < 16) {
      int c = tid;
      for (int r = 0; r < 16; r++) {
        float v;
        if (r < c) v = 0.f;
        else {
          v = (r == c) ? 1.f : 0.f;
          for (int s2 = c; s2 < r; s2++) v -= L[r][s2] * X[s2][c];
          v /= L[r][r];
        }
        X[r][c] = v;
      }
    }
    __syncthreads();
    for (int e = tid; e < 256; e += 64) outL[e] = X[e>>4][e&15];
    if (tid == 0) {
      float ld = 0.f;
      for (int j = 0; j < 16; j++) ld += logf(L[j][j]);
      *outld = ld;
    }
  } else {
    if (tid < 8) {
      int row = tid;
      float q[8], mx = -1e30f;
      for (int j = 0; j < 8; j++) { q[j] = Q[row*8+j]; mx = fmaxf(mx, q[j]); }
      float s = 0.f;
      for (int j = 0; j < 8; j++) s += __expf(q[j]-mx);
      float ls = logf(s);
      for (int j = 0; j < 8; j++) {
        float e = __expf(q[j]-mx-ls);
        prm[P_QEXP  + row*8 + j] = e;
        prm[P_QTEXP + j*8 + row] = e;
      }
    } else if (tid == 8) {
      float p[8], mx = -1e30f;
      for (int j = 0; j < 8; j++) { p[j] = pi[j]; mx = fmaxf(mx, p[j]); }
      float s = 0.f;
      for (int j = 0; j < 8; j++) s += __expf(p[j]-mx);
      float ls = logf(s);
      for (int j = 0; j < 8; j++) prm[P_LOGPI+j] = p[j]-mx-ls;
    }
  }
}

// ---------------- kernel 2: emissions (fp32), wave=(k,t), lane=b ----------
__global__ __launch_bounds__(256) void emisA_kernel(
    const float* __restrict__ z, const float* __restrict__ W1,
    const float* __restrict__ b1, const float* __restrict__ W2,
    const float* __restrict__ b2, const float* __restrict__ init_mean,
    const float* __restrict__ prm, float* __restrict__ lebuf)
{
  int b = threadIdx.x & 63;
  int wid = __builtin_amdgcn_readfirstlane(blockIdx.x * 4 + (threadIdx.x >> 6));
  int k = wid >> 11;          // wave-uniform
  int t = wid & 2047;         // wave-uniform
  float zc[16];
  {
    const float4* p4 = (const float4*)(z + (b*T_ + t)*LD_);
    float4 v0=p4[0], v1=p4[1], v2=p4[2], v3=p4[3];
    zc[0]=v0.x; zc[1]=v0.y; zc[2]=v0.z; zc[3]=v0.w;
    zc[4]=v1.x; zc[5]=v1.y; zc[6]=v1.z; zc[7]=v1.w;
    zc[8]=v2.x; zc[9]=v2.y; zc[10]=v2.z; zc[11]=v2.w;
    zc[12]=v3.x; zc[13]=v3.y; zc[14]=v3.z; zc[15]=v3.w;
  }
  float le;
  if (t == 0) {
    float diff[16];
    #pragma unroll
    for (int l = 0; l < 16; l++) diff[l] = zc[l] - init_mean[k*16+l];
    const float* Li = prm + P_LINV0 + k*256;
    float maha = 0.f;
    #pragma unroll
    for (int d = 0; d < 16; d++) {
      float y = 0.f;
      #pragma unroll
      for (int e = 0; e < 16; e++) y = __builtin_fmaf(Li[d*16+e], diff[e], y);
      maha = __builtin_fmaf(y, y, maha);
    }
    le = -0.5f*maha - prm[P_LD0+k] - 14.70301653f + prm[P_LOGPI+k];
  } else {
    float zp[16];
    {
      const float4* p4 = (const float4*)(z + (b*T_ + t - 1)*LD_);
      float4 v0=p4[0], v1=p4[1], v2=p4[2], v3=p4[3];
      zp[0]=v0.x; zp[1]=v0.y; zp[2]=v0.z; zp[3]=v0.w;
      zp[4]=v1.x; zp[5]=v1.y; zp[6]=v1.z; zp[7]=v1.w;
      zp[8]=v2.x; zp[9]=v2.y; zp[10]=v2.z; zp[11]=v2.w;
      zp[12]=v3.x; zp[13]=v3.y; zp[14]=v3.z; zp[15]=v3.w;
    }
    float h[64];
    #pragma unroll
    for (int hh = 0; hh < 64; hh++) {
      float a = b1[k*64+hh];
      #pragma unroll
      for (int l = 0; l < 16; l++) a = __builtin_fmaf(W1[k*1024 + hh*16 + l], zp[l], a);
      h[hh] = fmaxf(a, 0.f) + __logf(1.f + __expf(-fabsf(a)));
    }
    float diff[16];
    #pragma unroll
    for (int d = 0; d < 16; d++) {
      float mu = b2[k*16+d];
      #pragma unroll
      for (int hh = 0; hh < 64; hh++) mu = __builtin_fmaf(W2[k*1024 + d*64 + hh], h[hh], mu);
      diff[d] = zc[d] - mu;
    }
    const float* Li = prm + P_LINVT + k*256;
    float maha = 0.f;
    #pragma unroll
    for (int d = 0; d < 16; d++) {
      float y = 0.f;
      #pragma unroll
      for (int e = 0; e < 16; e++) y = __builtin_fmaf(Li[d*16+e], diff[e], y);
      maha = __builtin_fmaf(y, y, maha);
    }
    le = -0.5f*maha - prm[P_LDT+k] - 14.70301653f;
  }
  lebuf[t*512 + k*64 + b] = le;
}

// ---------------- fwd P1: per-(b,chunk) operator products (inline ehat) ------
__global__ __launch_bounds__(256) void fwdP1_kernel(
    const float* __restrict__ lebuf, const float* __restrict__ prm,
    float* __restrict__ pbuf)
{
  int g = (blockIdx.x*256 + threadIdx.x) >> 3;   // 0..8191
  int j = threadIdx.x & 7;
  int b = g & 63, c = g >> 6;                    // c 0..127
  float qtv[64];
  #pragma unroll
  for (int u = 0; u < 8; u++)
    #pragma unroll
    for (int v = 0; v < 8; v++)
      qtv[u*8+v] = prm[P_QTEXP + (j^u)*8 + (j^v)];
  float lev[16];
  #pragma unroll
  for (int u = 0; u < 16; u++) lev[u] = lebuf[(c*L_+u)*512 + j*64 + b];
  float pl[8];
  int ustart;
  if (c == 0) {
    float m = bfly_max8(lev[0]);
    float e = __expf(lev[0]-m);
    allg8(e, pl);                // P[:,j] = ehat_0 (all columns equal)
    ustart = 1;
  } else {
    #pragma unroll
    for (int u = 0; u < 8; u++) pl[u] = (u == 0) ? 1.f : 0.f;
    ustart = 0;
  }
  for (int s = ustart; s < 16; s++) {
    float m = bfly_max8(lev[s]);
    float e = __expf(lev[s]-m);
    float e8[8]; allg8(e, e8);
    float np[8];
    #pragma unroll
    for (int u = 0; u < 8; u++) {
      float acc = 0.f;
      #pragma unroll
      for (int v = 0; v < 8; v++) acc = __builtin_fmaf(qtv[u*8+v], pl[v], acc);
      np[u] = e8[u] * acc;
    }
    float mx = np[0];
    #pragma unroll
    for (int u = 1; u < 8; u++) mx = fmaxf(mx, np[u]);
    mx = bfly_max8(mx);
    float r = rcpnr(mx);
    #pragma unroll
    for (int u = 0; u < 8; u++) pl[u] = np[u] * r;
  }
  float4* dst = (float4*)(pbuf + g*64 + j*8);
  dst[0] = make_float4(pl[0], pl[1], pl[2], pl[3]);
  dst[1] = make_float4(pl[4], pl[5], pl[6], pl[7]);
}

// ---------------- fwd P2: serial chunk-boundary recursion, 8-deep prefetch ---
__global__ __launch_bounds__(512) void fwdP2_kernel(
    const float* __restrict__ pbuf, float* __restrict__ ain)
{
  int lane = threadIdx.x;
  int b = lane >> 3, i = lane & 7;
  float a = 0.125f;               // chunk 0's columns all equal -> dummy works
  float cur[8][8], nxt[8][8];
  #pragma unroll
  for (int u = 0; u < 8; u++)
    #pragma unroll
    for (int v = 0; v < 8; v++)
      cur[u][v] = pbuf[(u*64+b)*64 + (i^v)*8 + v];
  for (int tb = 0; tb < 128; tb += 8) {
    #pragma unroll
    for (int u = 0; u < 8; u++) {
      int c2 = tb + 8 + u; c2 = (c2 > 127) ? 127 : c2;
      #pragma unroll
      for (int v = 0; v < 8; v++) nxt[u][v] = pbuf[(c2*64+b)*64 + (i^v)*8 + v];
    }
    #pragma unroll
    for (int u = 0; u < 8; u++) {
      int c = tb + u;
      float aw[8]; allg8(a, aw);
      float s = 0.f;
      #pragma unroll
      for (int v = 0; v < 8; v++) s = __builtin_fmaf(cur[u][v], aw[v], s);
      float tot = bfly_sum8(s);
      float an = s * rcpnr(tot);
      if (c < 127) { a = an; ain[(c+1)*512 + b*8 + i] = a; }
    }
    #pragma unroll
    for (int u = 0; u < 8; u++)
      #pragma unroll
      for (int v = 0; v < 8; v++) cur[u][v] = nxt[u][v];
  }
}

// ---------------- fwd P3 (+ fused bwd chunk products) ------------------------
__global__ __launch_bounds__(256) void fwdP3_kernel(
    const float* __restrict__ lebuf, const float* __restrict__ prm,
    const float* __restrict__ ain, float* __restrict__ alpha,
    float* __restrict__ ebar, float* __restrict__ rbuf,
    float* __restrict__ rlog, float* __restrict__ out)
{
  int g = (blockIdx.x*256 + threadIdx.x) >> 3;
  int i = threadIdx.x & 7;
  int b = g & 63, c = g >> 6;
  int off = b*8 + i;
  float q[8];
  #pragma unroll
  for (int u = 0; u < 8; u++) q[u] = prm[P_QTEXP + i*8 + (i^u)];
  float lev[16];
  #pragma unroll
  for (int u = 0; u < 16; u++) lev[u] = lebuf[(c*L_+u)*512 + i*64 + b];
  float* logZ = out + OUT_LOGZ + b*T_;
  float eb_loc[16];
  float a;
  int ustart;
  if (c == 0) {
    float m0 = bfly_max8(lev[0]);
    float e0 = __expf(lev[0]-m0);
    float ct = bfly_sum8(e0);
    float r = rcpnr(ct);
    a = e0 * r;
    alpha[off] = a;
    eb_loc[0] = a;
    ebar[off] = a;
    if (i == 0) logZ[0] = m0 + __logf(ct);
    ustart = 1;
  } else {
    a = ain[c*512 + off];
    ustart = 0;
  }
  for (int u = ustart; u < 16; u++) {
    int t = c*L_ + u;
    float m = bfly_max8(lev[u]);
    float e = __expf(lev[u]-m);
    float w[8]; allg8(a, w);
    float dot = ((q[0]*w[0]+q[1]*w[1]) + (q[2]*w[2]+q[3]*w[3]))
              + ((q[4]*w[4]+q[5]*w[5]) + (q[6]*w[6]+q[7]*w[7]));
    float p = e * dot;
    float ct = bfly_sum8(p);
    float r = rcpnr(ct);
    a = p * r;
    alpha[t*512 + off] = a;
    float eb = e * r;
    eb_loc[u] = eb;
    ebar[t*512 + off] = eb;
    if (i == 0) logZ[t] = m + __logf(ct);
  }
  // fused backward chunk product: R'_c = Q E_{cL+1} ... Q E_{cL+15}
  float qv[64];
  #pragma unroll
  for (int u = 0; u < 8; u++)
    #pragma unroll
    for (int v = 0; v < 8; v++)
      qv[u*8+v] = prm[P_QEXP + (i^u)*8 + (i^v)];
  float rl[8];
  #pragma unroll
  for (int u = 0; u < 8; u++) rl[u] = (u == 0) ? 1.f : 0.f;
  float lsc = 0.f;
  #pragma unroll
  for (int s = 15; s >= 1; s--) {
    float e8[8]; allg8(eb_loc[s], e8);
    float nr[8];
    #pragma unroll
    for (int u = 0; u < 8; u++) {
      float acc = 0.f;
      #pragma unroll
      for (int v = 0; v < 8; v++) acc = __builtin_fmaf(qv[u*8+v], e8[v]*rl[v], acc);
      nr[u] = acc;
    }
    float mx = nr[0];
    #pragma unroll
    for (int u = 1; u < 8; u++) mx = fmaxf(mx, nr[u]);
    mx = bfly_max8(mx);
    float r = rcpnr(mx);
    #pragma unroll
    for (int u = 0; u < 8; u++) rl[u] = nr[u] * r;
    lsc += __logf(mx);
  }
  float4* dst = (float4*)(rbuf + g*64 + i*8);
  dst[0] = make_float4(rl[0], rl[1], rl[2], rl[3]);
  dst[1] = make_float4(rl[4], rl[5], rl[6], rl[7]);
  if (i == 0) rlog[g] = lsc;
}

// ---------------- bwd P2: serial boundary recursion -> chunk-bottom betas ----
__global__ __launch_bounds__(512) void bwdP2_kernel(
    const float* __restrict__ rbuf, const float* __restrict__ rlog,
    const float* __restrict__ ebar, const float* __restrict__ prm,
    float* __restrict__ sb)
{
  int lane = threadIdx.x;
  int b = lane >> 3, i = lane & 7;
  float qe[8];
  #pragma unroll
  for (int u = 0; u < 8; u++) qe[u] = prm[P_QEXP + i*8 + (i^u)];
  float bt = 1.f;                         // beta at t=2047 (top of chunk 127)
  float cur[8][8], nxt[8][8], crl[8], nrl[8], ce0[8], ne0[8];
  #pragma unroll
  for (int u = 0; u < 8; u++) {
    int c = 127 - u;
    #pragma unroll
    for (int v = 0; v < 8; v++) cur[u][v] = rbuf[(c*64+b)*64 + (i^v)*8 + v];
    crl[u] = rlog[c*64 + b];
    ce0[u] = ebar[(c*L_)*512 + b*8 + i];
  }
  for (int tb = 127; tb >= 7; tb -= 8) {
    #pragma unroll
    for (int u = 0; u < 8; u++) {
      int c2 = tb - 8 - u; c2 = (c2 < 1) ? 1 : c2;
      #pragma unroll
      for (int v = 0; v < 8; v++) nxt[u][v] = rbuf[(c2*64+b)*64 + (i^v)*8 + v];
      nrl[u] = rlog[c2*64 + b];
      ne0[u] = ebar[(c2*L_)*512 + b*8 + i];
    }
    #pragma unroll
    for (int u = 0; u < 8; u++) {
      int c = tb - u;
      if (c >= 1) {
        float btw[8]; allg8(bt, btw);
        float y = 0.f;
        #pragma unroll
        for (int v = 0; v < 8; v++) y = __builtin_fmaf(cur[u][v], btw[v], y);
        y *= __expf(crl[u]);              // beta at t = c*16 (actual scale)
        sb[c*512 + b*8 + i] = y;
        float w[8]; allg8(ce0[u]*y, w);
        float nb = 0.f;
        #pragma unroll
        for (int v = 0; v < 8; v++) nb = __builtin_fmaf(qe[v], w[v], nb);
        bt = nb;                          // beta at t = c*16-1 (top of c-1)
      }
    }
    #pragma unroll
    for (int u = 0; u < 8; u++) {
      #pragma unroll
      for (int v = 0; v < 8; v++) cur[u][v] = nxt[u][v];
      crl[u] = nrl[u]; ce0[u] = ne0[u];
    }
  }
}

// ---------------- bwd P3 fused with gamma/paired emission --------------------
__global__ __launch_bounds__(256) void bwdP3_kernel(
    const float* __restrict__ alpha, const float* __restrict__ ebar,
    const float* __restrict__ sb, const float* __restrict__ prm,
    float* __restrict__ out)
{
  int g = (blockIdx.x*256 + threadIdx.x) >> 3;
  int i = threadIdx.x & 7;
  int b = g & 63, c = g >> 6;
  int off = b*8 + i;
  float q[8];
  #pragma unroll
  for (int u = 0; u < 8; u++) q[u] = prm[P_QEXP + i*8 + (i^u)];
  float av[16], ev[16];
  #pragma unroll
  for (int u = 0; u < 16; u++) av[u] = alpha[(c*L_+u)*512 + off];
  #pragma unroll
  for (int u = 1; u < 16; u++) ev[u] = ebar[(c*L_+u)*512 + off];
  float* po = out + OUT_PAIRED + b*((T_-1)*64);
  float* go = out + b*(T_*K_);
  float bb;
  if (c == 127) {
    bb = 1.f;
    go[2047*8 + i] = av[15];             // gamma at t=2047 (beta=1)
  } else {
    float ev16 = ebar[((c+1)*L_)*512 + off];
    float sbv  = sb[(c+1)*512 + off];
    float w[8]; allg8(ev16*sbv, w);
    bb = ((q[0]*w[0]+q[1]*w[1]) + (q[2]*w[2]+q[3]*w[3]))
       + ((q[4]*w[4]+q[5]*w[5]) + (q[6]*w[6]+q[7]*w[7]));
    int t = c*L_ + 15;
    #pragma unroll
    for (int u2 = 0; u2 < 8; u2++)
      po[t*64 + i*8 + (i^u2)] = av[15] * q[u2] * w[u2];
    go[t*8 + i] = av[15] * bb;
  }
  #pragma unroll
  for (int u = 15; u >= 1; u--) {
    float w[8]; allg8(ev[u]*bb, w);
    float nb = ((q[0]*w[0]+q[1]*w[1]) + (q[2]*w[2]+q[3]*w[3]))
             + ((q[4]*w[4]+q[5]*w[5]) + (q[6]*w[6]+q[7]*w[7]));
    int t = c*L_ + u - 1;
    #pragma unroll
    for (int u2 = 0; u2 < 8; u2++)
      po[t*64 + i*8 + (i^u2)] = av[u-1] * q[u2] * w[u2];
    go[t*8 + i] = av[u-1] * nb;
    bb = nb;
  }
}

extern "C" void kernel_launch(void* const* d_in, const int* in_sizes, int n_in,
                              void* d_out, int out_size, void* d_ws, size_t ws_size,
                              hipStream_t stream) {
  const float* z         = (const float*)d_in[0];
  const float* pi        = (const float*)d_in[1];
  const float* Q         = (const float*)d_in[2];
  const float* init_mean = (const float*)d_in[3];
  const float* init_cov  = (const float*)d_in[4];
  const float* covs      = (const float*)d_in[5];
  const float* W1        = (const float*)d_in[6];
  const float* b1        = (const float*)d_in[7];
  const float* W2        = (const float*)d_in[8];
  const float* b2        = (const float*)d_in[9];
  float* out = (float*)d_out;
  float* ws  = (float*)d_ws;

  prep_kernel<<<17, 64, 0, stream>>>(pi, Q, init_cov, covs, ws + OFF_PRM);
  emisA_kernel<<<4096, 256, 0, stream>>>(z, W1, b1, W2, b2, init_mean,
                                         ws + OFF_PRM, ws + OFF_LE);
  fwdP1_kernel<<<256, 256, 0, stream>>>(ws + OFF_LE, ws + OFF_PRM, ws + OFF_PBUF);
  fwdP2_kernel<<<1, 512, 0, stream>>>(ws + OFF_PBUF, ws + OFF_AIN);
  fwdP3_kernel<<<256, 256, 0, stream>>>(ws + OFF_LE, ws + OFF_PRM, ws + OFF_AIN,
                                        ws + OFF_ALPHA, ws + OFF_EBAR,
                                        ws + OFF_PBUF, ws + OFF_RLOG, out);
  bwdP2_kernel<<<1, 512, 0, stream>>>(ws + OFF_PBUF, ws + OFF_RLOG,
                                      ws + OFF_EBAR, ws + OFF_PRM, ws + OFF_SB);
  bwdP3_kernel<<<256, 256, 0, stream>>>(ws + OFF_ALPHA, ws + OFF_EBAR,
                                        ws + OFF_SB, ws + OFF_PRM, out);
}

// Round 6
// 317.914 us; speedup vs baseline: 2.3190x; 2.3190x over previous
//
#include <hip/hip_runtime.h>

#define B_ 64
#define T_ 2048
#define LD_ 16
#define HD_ 64
#define K_ 8
#define L_ 16
#define C_ 128

// ---------------- workspace layout (floats) ----------------
constexpr int OFF_LE    = 0;                    // T*B*K
constexpr int OFF_ALPHA = 1048576;              // T*B*K
constexpr int OFF_EBAR  = 2097152;              // T*B*K
constexpr int OFF_PBUF  = 3145728;              // C*B*64 = 524288 (fwd P rows; rbuf aliases after fwdP2)
constexpr int OFF_RLOG  = 3670016;              // C*B = 8192
constexpr int OFF_AIN   = 3678208;              // C*B*K = 65536
constexpr int OFF_SB    = 3743744;              // C*B*K = 65536
constexpr int OFF_PRM   = 3809280;              // params; total ~15.3 MB

// params region (relative to OFF_PRM), float-indexed
constexpr int P_LINV0 = 0;       // 8*16*16
constexpr int P_LINVT = 2048;    // 8*16*16
constexpr int P_LD0   = 4096;    // 8
constexpr int P_LDT   = 4104;    // 8
constexpr int P_LOGPI = 4112;    // 8
constexpr int P_QEXP  = 4120;    // 64
constexpr int P_QTEXP = 4184;    // 64

// output layout (floats)
constexpr int OUT_PAIRED = B_*T_*K_;                       // 1048576
constexpr int OUT_LOGZ   = OUT_PAIRED + B_*(T_-1)*K_*K_;   // 9433088

// ---------------- DPP helpers (aligned groups of 8 lanes) ----------------
template<int CTRL>
__device__ __forceinline__ float dppmov(float x) {
  int xi = __float_as_int(x);
  int r = __builtin_amdgcn_update_dpp(xi, xi, CTRL, 0xF, 0xF, true);
  return __int_as_float(r);
}
// 0xB1=xor1, 0x4E=xor2, 0x141=row_half_mirror=xor7 (within 8)
__device__ __forceinline__ void allg8(float v, float w[8]) {
  w[0] = v;
  w[1] = dppmov<0xB1>(v);
  w[2] = dppmov<0x4E>(v);
  w[3] = dppmov<0x4E>(w[1]);
  w[7] = dppmov<0x141>(v);
  w[6] = dppmov<0xB1>(w[7]);
  w[5] = dppmov<0x4E>(w[7]);
  w[4] = dppmov<0x4E>(w[6]);
}
// xor_v on a single value (used for column->row layout transpose)
template<int V> __device__ __forceinline__ float xorg8(float x);
template<> __device__ __forceinline__ float xorg8<0>(float x) { return x; }
template<> __device__ __forceinline__ float xorg8<1>(float x) { return dppmov<0xB1>(x); }
template<> __device__ __forceinline__ float xorg8<2>(float x) { return dppmov<0x4E>(x); }
template<> __device__ __forceinline__ float xorg8<3>(float x) { return dppmov<0x4E>(dppmov<0xB1>(x)); }
template<> __device__ __forceinline__ float xorg8<4>(float x) { return dppmov<0x4E>(dppmov<0xB1>(dppmov<0x141>(x))); }
template<> __device__ __forceinline__ float xorg8<5>(float x) { return dppmov<0x4E>(dppmov<0x141>(x)); }
template<> __device__ __forceinline__ float xorg8<6>(float x) { return dppmov<0xB1>(dppmov<0x141>(x)); }
template<> __device__ __forceinline__ float xorg8<7>(float x) { return dppmov<0x141>(x); }

__device__ __forceinline__ float bfly_sum8(float x) {
  x += dppmov<0xB1>(x); x += dppmov<0x4E>(x); x += dppmov<0x141>(x); return x;
}
__device__ __forceinline__ float bfly_max8(float x) {
  x = fmaxf(x, dppmov<0xB1>(x)); x = fmaxf(x, dppmov<0x4E>(x)); x = fmaxf(x, dppmov<0x141>(x)); return x;
}
__device__ __forceinline__ float rcpnr(float x) {
  float r0 = __builtin_amdgcn_rcpf(x);
  return r0 * __builtin_fmaf(-x, r0, 2.0f);
}

// column-xor layout cl[u]=M[j^u][j] (lane j) -> row-xor layout rv[v]=M[j][j^v]
__device__ __forceinline__ void col2row(const float cl[8], float rv[8]) {
  rv[0] = cl[0];
  rv[1] = xorg8<1>(cl[1]);
  rv[2] = xorg8<2>(cl[2]);
  rv[3] = xorg8<3>(cl[3]);
  rv[4] = xorg8<4>(cl[4]);
  rv[5] = xorg8<5>(cl[5]);
  rv[6] = xorg8<6>(cl[6]);
  rv[7] = xorg8<7>(cl[7]);
}

// ---------------- kernel 1: Cholesky / softmax params ----------------
__global__ __launch_bounds__(64) void prep_kernel(
    const float* __restrict__ pi, const float* __restrict__ Q,
    const float* __restrict__ init_cov, const float* __restrict__ covs,
    float* __restrict__ prm)
{
  int tid = threadIdx.x;
  int blk = blockIdx.x;
  if (blk < 16) {
    int k = blk & 7;
    const float* C = (blk < 8 ? init_cov : covs) + k*256;
    float* outL  = prm + (blk < 8 ? P_LINV0 : P_LINVT) + k*256;
    float* outld = prm + (blk < 8 ? P_LD0   : P_LDT)   + k;
    __shared__ float S[16][17], L[16][17], X[16][17];
    for (int e = tid; e < 256; e += 64) {
      int r = e >> 4, c = e & 15;
      float s = (r == c) ? 1e-6f : 0.f;
      for (int l = 0; l < 16; l++) s += C[r*16+l] * C[c*16+l];
      S[r][c] = s;
    }
    __syncthreads();
    for (int j = 0; j < 16; j++) {
      if (tid == 0) L[j][j] = sqrtf(S[j][j]);
      __syncthreads();
      if (tid > j && tid < 16) L[tid][j] = S[tid][j] / L[j][j];
      __syncthreads();
      if (tid > j && tid < 16) {
        float ltj = L[tid][j];
        for (int c = j+1; c <= tid; c++) S[tid][c] -= ltj * L[c][j];
      }
      __syncthreads();
    }
    if (tid < 16) {
      int c = tid;
      for (int r = 0; r < 16; r++) {
        float v;
        if (r < c) v = 0.f;
        else {
          v = (r == c) ? 1.f : 0.f;
          for (int s2 = c; s2 < r; s2++) v -= L[r][s2] * X[s2][c];
          v /= L[r][r];
        }
        X[r][c] = v;
      }
    }
    __syncthreads();
    for (int e = tid; e < 256; e += 64) outL[e] = X[e>>4][e&15];
    if (tid == 0) {
      float ld = 0.f;
      for (int j = 0; j < 16; j++) ld += logf(L[j][j]);
      *outld = ld;
    }
  } else {
    if (tid < 8) {
      int row = tid;
      float q[8], mx = -1e30f;
      for (int j = 0; j < 8; j++) { q[j] = Q[row*8+j]; mx = fmaxf(mx, q[j]); }
      float s = 0.f;
      for (int j = 0; j < 8; j++) s += __expf(q[j]-mx);
      float ls = logf(s);
      for (int j = 0; j < 8; j++) {
        float e = __expf(q[j]-mx-ls);
        prm[P_QEXP  + row*8 + j] = e;
        prm[P_QTEXP + j*8 + row] = e;
      }
    } else if (tid == 8) {
      float p[8], mx = -1e30f;
      for (int j = 0; j < 8; j++) { p[j] = pi[j]; mx = fmaxf(mx, p[j]); }
      float s = 0.f;
      for (int j = 0; j < 8; j++) s += __expf(p[j]-mx);
      float ls = logf(s);
      for (int j = 0; j < 8; j++) prm[P_LOGPI+j] = p[j]-mx-ls;
    }
  }
}

// ---------------- kernel 2: emissions (fp32), wave=(k,t), lane=b ----------
__global__ __launch_bounds__(256) void emisA_kernel(
    const float* __restrict__ z, const float* __restrict__ W1,
    const float* __restrict__ b1, const float* __restrict__ W2,
    const float* __restrict__ b2, const float* __restrict__ init_mean,
    const float* __restrict__ prm, float* __restrict__ lebuf)
{
  int b = threadIdx.x & 63;
  int wid = __builtin_amdgcn_readfirstlane(blockIdx.x * 4 + (threadIdx.x >> 6));
  int k = wid >> 11;          // wave-uniform
  int t = wid & 2047;         // wave-uniform
  float zc[16];
  {
    const float4* p4 = (const float4*)(z + (b*T_ + t)*LD_);
    float4 v0=p4[0], v1=p4[1], v2=p4[2], v3=p4[3];
    zc[0]=v0.x; zc[1]=v0.y; zc[2]=v0.z; zc[3]=v0.w;
    zc[4]=v1.x; zc[5]=v1.y; zc[6]=v1.z; zc[7]=v1.w;
    zc[8]=v2.x; zc[9]=v2.y; zc[10]=v2.z; zc[11]=v2.w;
    zc[12]=v3.x; zc[13]=v3.y; zc[14]=v3.z; zc[15]=v3.w;
  }
  float le;
  if (t == 0) {
    float diff[16];
    #pragma unroll
    for (int l = 0; l < 16; l++) diff[l] = zc[l] - init_mean[k*16+l];
    const float* Li = prm + P_LINV0 + k*256;
    float maha = 0.f;
    #pragma unroll
    for (int d = 0; d < 16; d++) {
      float y = 0.f;
      #pragma unroll
      for (int e = 0; e < 16; e++) y = __builtin_fmaf(Li[d*16+e], diff[e], y);
      maha = __builtin_fmaf(y, y, maha);
    }
    le = -0.5f*maha - prm[P_LD0+k] - 14.70301653f + prm[P_LOGPI+k];
  } else {
    float zp[16];
    {
      const float4* p4 = (const float4*)(z + (b*T_ + t - 1)*LD_);
      float4 v0=p4[0], v1=p4[1], v2=p4[2], v3=p4[3];
      zp[0]=v0.x; zp[1]=v0.y; zp[2]=v0.z; zp[3]=v0.w;
      zp[4]=v1.x; zp[5]=v1.y; zp[6]=v1.z; zp[7]=v1.w;
      zp[8]=v2.x; zp[9]=v2.y; zp[10]=v2.z; zp[11]=v2.w;
      zp[12]=v3.x; zp[13]=v3.y; zp[14]=v3.z; zp[15]=v3.w;
    }
    float h[64];
    #pragma unroll
    for (int hh = 0; hh < 64; hh++) {
      float a = b1[k*64+hh];
      #pragma unroll
      for (int l = 0; l < 16; l++) a = __builtin_fmaf(W1[k*1024 + hh*16 + l], zp[l], a);
      h[hh] = fmaxf(a, 0.f) + __logf(1.f + __expf(-fabsf(a)));
    }
    float diff[16];
    #pragma unroll
    for (int d = 0; d < 16; d++) {
      float mu = b2[k*16+d];
      #pragma unroll
      for (int hh = 0; hh < 64; hh++) mu = __builtin_fmaf(W2[k*1024 + d*64 + hh], h[hh], mu);
      diff[d] = zc[d] - mu;
    }
    const float* Li = prm + P_LINVT + k*256;
    float maha = 0.f;
    #pragma unroll
    for (int d = 0; d < 16; d++) {
      float y = 0.f;
      #pragma unroll
      for (int e = 0; e < 16; e++) y = __builtin_fmaf(Li[d*16+e], diff[e], y);
      maha = __builtin_fmaf(y, y, maha);
    }
    le = -0.5f*maha - prm[P_LDT+k] - 14.70301653f;
  }
  lebuf[t*512 + k*64 + b] = le;
}

// ---------------- fwd P1: per-(b,chunk) operator products -> ROW layout ------
__global__ __launch_bounds__(256) void fwdP1_kernel(
    const float* __restrict__ lebuf, const float* __restrict__ prm,
    float* __restrict__ pbuf)
{
  int g = (blockIdx.x*256 + threadIdx.x) >> 3;   // 0..8191
  int j = threadIdx.x & 7;
  int b = g & 63, c = g >> 6;                    // c 0..127
  float qtv[64];
  #pragma unroll
  for (int u = 0; u < 8; u++)
    #pragma unroll
    for (int v = 0; v < 8; v++)
      qtv[u*8+v] = prm[P_QTEXP + (j^u)*8 + (j^v)];
  float lev[16];
  #pragma unroll
  for (int u = 0; u < 16; u++) lev[u] = lebuf[(c*L_+u)*512 + j*64 + b];
  float pl[8];
  int ustart;
  if (c == 0) {
    float m = bfly_max8(lev[0]);
    float e = __expf(lev[0]-m);
    allg8(e, pl);                // P[:,j] = ehat_0 (all columns equal)
    ustart = 1;
  } else {
    #pragma unroll
    for (int u = 0; u < 8; u++) pl[u] = (u == 0) ? 1.f : 0.f;
    ustart = 0;
  }
  for (int s = ustart; s < 16; s++) {
    float m = bfly_max8(lev[s]);
    float e = __expf(lev[s]-m);
    float e8[8]; allg8(e, e8);
    float np[8];
    #pragma unroll
    for (int u = 0; u < 8; u++) {
      float acc = 0.f;
      #pragma unroll
      for (int v = 0; v < 8; v++) acc = __builtin_fmaf(qtv[u*8+v], pl[v], acc);
      np[u] = e8[u] * acc;
    }
    float mx = np[0];
    #pragma unroll
    for (int u = 1; u < 8; u++) mx = fmaxf(mx, np[u]);
    mx = bfly_max8(mx);
    float r = rcpnr(mx);
    #pragma unroll
    for (int u = 0; u < 8; u++) pl[u] = np[u] * r;
  }
  // transpose column-xor -> row-xor so fwdP2 reads contiguous float4s
  float rv[8]; col2row(pl, rv);
  float4* dst = (float4*)(pbuf + g*64 + j*8);
  dst[0] = make_float4(rv[0], rv[1], rv[2], rv[3]);
  dst[1] = make_float4(rv[4], rv[5], rv[6], rv[7]);
}

// ---------------- fwd P2: serial boundary recursion, depth-4 float4 ring -----
__global__ __launch_bounds__(512) void fwdP2_kernel(
    const float* __restrict__ pbuf, float* __restrict__ ain)
{
  int lane = threadIdx.x;
  int b = lane >> 3, i = lane & 7;
  const float4* base = (const float4*)pbuf;   // (c*64+b)*16 + i*2
  float4 r0[4], r1[4], n0[4], n1[4];
  #pragma unroll
  for (int u = 0; u < 4; u++) {
    r0[u] = base[(u*64+b)*16 + i*2];
    r1[u] = base[(u*64+b)*16 + i*2 + 1];
  }
  float a = 0.125f;               // chunk 0's columns all equal -> dummy works
  for (int tb = 0; tb < 128; tb += 4) {
    #pragma unroll
    for (int u = 0; u < 4; u++) {
      int c2 = tb + 4 + u; c2 = (c2 > 127) ? 127 : c2;
      n0[u] = base[(c2*64+b)*16 + i*2];
      n1[u] = base[(c2*64+b)*16 + i*2 + 1];
    }
    #pragma unroll
    for (int u = 0; u < 4; u++) {
      int c = tb + u;
      float aw[8]; allg8(a, aw);
      float s = ((r0[u].x*aw[0] + r0[u].y*aw[1]) + (r0[u].z*aw[2] + r0[u].w*aw[3]))
              + ((r1[u].x*aw[4] + r1[u].y*aw[5]) + (r1[u].z*aw[6] + r1[u].w*aw[7]));
      float tot = bfly_sum8(s);
      float an = s * rcpnr(tot);
      if (c < 127) { a = an; ain[(c+1)*512 + b*8 + i] = a; }
    }
    #pragma unroll
    for (int u = 0; u < 4; u++) { r0[u] = n0[u]; r1[u] = n1[u]; }
  }
}

// ---------------- fwd P3 (+ fused bwd chunk products -> ROW layout) ----------
__global__ __launch_bounds__(256) void fwdP3_kernel(
    const float* __restrict__ lebuf, const float* __restrict__ prm,
    const float* __restrict__ ain, float* __restrict__ alpha,
    float* __restrict__ ebar, float* __restrict__ rbuf,
    float* __restrict__ rlog, float* __restrict__ out)
{
  int g = (blockIdx.x*256 + threadIdx.x) >> 3;
  int i = threadIdx.x & 7;
  int b = g & 63, c = g >> 6;
  int off = b*8 + i;
  float q[8];
  #pragma unroll
  for (int u = 0; u < 8; u++) q[u] = prm[P_QTEXP + i*8 + (i^u)];
  float lev[16];
  #pragma unroll
  for (int u = 0; u < 16; u++) lev[u] = lebuf[(c*L_+u)*512 + i*64 + b];
  float* logZ = out + OUT_LOGZ + b*T_;
  float eb_loc[16];
  float a;
  int ustart;
  if (c == 0) {
    float m0 = bfly_max8(lev[0]);
    float e0 = __expf(lev[0]-m0);
    float ct = bfly_sum8(e0);
    float r = rcpnr(ct);
    a = e0 * r;
    alpha[off] = a;
    eb_loc[0] = a;
    ebar[off] = a;
    if (i == 0) logZ[0] = m0 + __logf(ct);
    ustart = 1;
  } else {
    a = ain[c*512 + off];
    ustart = 0;
  }
  for (int u = ustart; u < 16; u++) {
    int t = c*L_ + u;
    float m = bfly_max8(lev[u]);
    float e = __expf(lev[u]-m);
    float w[8]; allg8(a, w);
    float dot = ((q[0]*w[0]+q[1]*w[1]) + (q[2]*w[2]+q[3]*w[3]))
              + ((q[4]*w[4]+q[5]*w[5]) + (q[6]*w[6]+q[7]*w[7]));
    float p = e * dot;
    float ct = bfly_sum8(p);
    float r = rcpnr(ct);
    a = p * r;
    alpha[t*512 + off] = a;
    float eb = e * r;
    eb_loc[u] = eb;
    ebar[t*512 + off] = eb;
    if (i == 0) logZ[t] = m + __logf(ct);
  }
  // fused backward chunk product: R_c = Q E_{cL+1} ... Q E_{cL+15}
  float qv[64];
  #pragma unroll
  for (int u = 0; u < 8; u++)
    #pragma unroll
    for (int v = 0; v < 8; v++)
      qv[u*8+v] = prm[P_QEXP + (i^u)*8 + (i^v)];
  float rl[8];
  #pragma unroll
  for (int u = 0; u < 8; u++) rl[u] = (u == 0) ? 1.f : 0.f;
  float lsc = 0.f;
  #pragma unroll
  for (int s = 15; s >= 1; s--) {
    float e8[8]; allg8(eb_loc[s], e8);
    float nr[8];
    #pragma unroll
    for (int u = 0; u < 8; u++) {
      float acc = 0.f;
      #pragma unroll
      for (int v = 0; v < 8; v++) acc = __builtin_fmaf(qv[u*8+v], e8[v]*rl[v], acc);
      nr[u] = acc;
    }
    float mx = nr[0];
    #pragma unroll
    for (int u = 1; u < 8; u++) mx = fmaxf(mx, nr[u]);
    mx = bfly_max8(mx);
    float r = rcpnr(mx);
    #pragma unroll
    for (int u = 0; u < 8; u++) rl[u] = nr[u] * r;
    lsc += __logf(mx);
  }
  float rv[8]; col2row(rl, rv);
  float4* dst = (float4*)(rbuf + g*64 + i*8);
  dst[0] = make_float4(rv[0], rv[1], rv[2], rv[3]);
  dst[1] = make_float4(rv[4], rv[5], rv[6], rv[7]);
  if (i == 0) rlog[g] = lsc;
}

// ---------------- bwd P2: serial boundary recursion, depth-4 float4 ring -----
__global__ __launch_bounds__(512) void bwdP2_kernel(
    const float* __restrict__ rbuf, const float* __restrict__ rlog,
    const float* __restrict__ ebar, const float* __restrict__ prm,
    float* __restrict__ sb)
{
  int lane = threadIdx.x;
  int b = lane >> 3, i = lane & 7;
  float qe[8];
  #pragma unroll
  for (int u = 0; u < 8; u++) qe[u] = prm[P_QEXP + i*8 + (i^u)];
  const float4* base = (const float4*)rbuf;
  float4 r0[4], r1[4], n0[4], n1[4];
  float crl[4], nrl[4], ce0[4], ne0[4];
  #pragma unroll
  for (int u = 0; u < 4; u++) {
    int c = 127 - u;
    r0[u] = base[(c*64+b)*16 + i*2];
    r1[u] = base[(c*64+b)*16 + i*2 + 1];
    crl[u] = rlog[c*64 + b];
    ce0[u] = ebar[(c*L_)*512 + b*8 + i];
  }
  float bt = 1.f;                         // beta at t=2047 (top of chunk 127)
  for (int tb = 127; tb >= 3; tb -= 4) {
    #pragma unroll
    for (int u = 0; u < 4; u++) {
      int c2 = tb - 4 - u; c2 = (c2 < 1) ? 1 : c2;
      n0[u] = base[(c2*64+b)*16 + i*2];
      n1[u] = base[(c2*64+b)*16 + i*2 + 1];
      nrl[u] = rlog[c2*64 + b];
      ne0[u] = ebar[(c2*L_)*512 + b*8 + i];
    }
    #pragma unroll
    for (int u = 0; u < 4; u++) {
      int c = tb - u;
      if (c >= 1) {
        float btw[8]; allg8(bt, btw);
        float y = ((r0[u].x*btw[0] + r0[u].y*btw[1]) + (r0[u].z*btw[2] + r0[u].w*btw[3]))
                + ((r1[u].x*btw[4] + r1[u].y*btw[5]) + (r1[u].z*btw[6] + r1[u].w*btw[7]));
        y *= __expf(crl[u]);              // beta at t = c*16 (actual scale)
        sb[c*512 + b*8 + i] = y;
        float w[8]; allg8(ce0[u]*y, w);
        float nb = 0.f;
        #pragma unroll
        for (int v = 0; v < 8; v++) nb = __builtin_fmaf(qe[v], w[v], nb);
        bt = nb;                          // beta at t = c*16-1 (top of c-1)
      }
    }
    #pragma unroll
    for (int u = 0; u < 4; u++) {
      r0[u] = n0[u]; r1[u] = n1[u];
      crl[u] = nrl[u]; ce0[u] = ne0[u];
    }
  }
}

// ---------------- bwd P3 fused with gamma/paired emission --------------------
__global__ __launch_bounds__(256) void bwdP3_kernel(
    const float* __restrict__ alpha, const float* __restrict__ ebar,
    const float* __restrict__ sb, const float* __restrict__ prm,
    float* __restrict__ out)
{
  int g = (blockIdx.x*256 + threadIdx.x) >> 3;
  int i = threadIdx.x & 7;
  int b = g & 63, c = g >> 6;
  int off = b*8 + i;
  float q[8];
  #pragma unroll
  for (int u = 0; u < 8; u++) q[u] = prm[P_QEXP + i*8 + (i^u)];
  float av[16], ev[16];
  #pragma unroll
  for (int u = 0; u < 16; u++) av[u] = alpha[(c*L_+u)*512 + off];
  #pragma unroll
  for (int u = 1; u < 16; u++) ev[u] = ebar[(c*L_+u)*512 + off];
  float* po = out + OUT_PAIRED + b*((T_-1)*64);
  float* go = out + b*(T_*K_);
  float bb;
  if (c == 127) {
    bb = 1.f;
    go[2047*8 + i] = av[15];             // gamma at t=2047 (beta=1)
  } else {
    float ev16 = ebar[((c+1)*L_)*512 + off];
    float sbv  = sb[(c+1)*512 + off];
    float w[8]; allg8(ev16*sbv, w);
    bb = ((q[0]*w[0]+q[1]*w[1]) + (q[2]*w[2]+q[3]*w[3]))
       + ((q[4]*w[4]+q[5]*w[5]) + (q[6]*w[6]+q[7]*w[7]));
    int t = c*L_ + 15;
    #pragma unroll
    for (int u2 = 0; u2 < 8; u2++)
      po[t*64 + i*8 + (i^u2)] = av[15] * q[u2] * w[u2];
    go[t*8 + i] = av[15] * bb;
  }
  #pragma unroll
  for (int u = 15; u >= 1; u--) {
    float w[8]; allg8(ev[u]*bb, w);
    float nb = ((q[0]*w[0]+q[1]*w[1]) + (q[2]*w[2]+q[3]*w[3]))
             + ((q[4]*w[4]+q[5]*w[5]) + (q[6]*w[6]+q[7]*w[7]));
    int t = c*L_ + u - 1;
    #pragma unroll
    for (int u2 = 0; u2 < 8; u2++)
      po[t*64 + i*8 + (i^u2)] = av[u-1] * q[u2] * w[u2];
    go[t*8 + i] = av[u-1] * nb;
    bb = nb;
  }
}

extern "C" void kernel_launch(void* const* d_in, const int* in_sizes, int n_in,
                              void* d_out, int out_size, void* d_ws, size_t ws_size,
                              hipStream_t stream) {
  const float* z         = (const float*)d_in[0];
  const float* pi        = (const float*)d_in[1];
  const float* Q         = (const float*)d_in[2];
  const float* init_mean = (const float*)d_in[3];
  const float* init_cov  = (const float*)d_in[4];
  const float* covs      = (const float*)d_in[5];
  const float* W1        = (const float*)d_in[6];
  const float* b1        = (const float*)d_in[7];
  const float* W2        = (const float*)d_in[8];
  const float* b2        = (const float*)d_in[9];
  float* out = (float*)d_out;
  float* ws  = (float*)d_ws;

  prep_kernel<<<17, 64, 0, stream>>>(pi, Q, init_cov, covs, ws + OFF_PRM);
  emisA_kernel<<<4096, 256, 0, stream>>>(z, W1, b1, W2, b2, init_mean,
                                         ws + OFF_PRM, ws + OFF_LE);
  fwdP1_kernel<<<256, 256, 0, stream>>>(ws + OFF_LE, ws + OFF_PRM, ws + OFF_PBUF);
  fwdP2_kernel<<<1, 512, 0, stream>>>(ws + OFF_PBUF, ws + OFF_AIN);
  fwdP3_kernel<<<256, 256, 0, stream>>>(ws + OFF_LE, ws + OFF_PRM, ws + OFF_AIN,
                                        ws + OFF_ALPHA, ws + OFF_EBAR,
                                        ws + OFF_PBUF, ws + OFF_RLOG, out);
  bwdP2_kernel<<<1, 512, 0, stream>>>(ws + OFF_PBUF, ws + OFF_RLOG,
                                      ws + OFF_EBAR, ws + OFF_PRM, ws + OFF_SB);
  bwdP3_kernel<<<256, 256, 0, stream>>>(ws + OFF_ALPHA, ws + OFF_EBAR,
                                        ws + OFF_SB, ws + OFF_PRM, out);
}

// Round 7
// 296.597 us; speedup vs baseline: 2.4857x; 1.0719x over previous
//
#include <hip/hip_runtime.h>

#define B_ 64
#define T_ 2048
#define LD_ 16
#define HD_ 64
#define K_ 8
#define L_ 16
#define C_ 128
#define S_ 16   // supers (8 chunks each)

typedef float f2 __attribute__((ext_vector_type(2)));

#if defined(__has_builtin)
#if __has_builtin(__builtin_elementwise_fma)
#define HAVE_EFMA 1
#endif
#endif
static __device__ __forceinline__ f2 efma(f2 a, f2 b, f2 c) {
#ifdef HAVE_EFMA
  return __builtin_elementwise_fma(a, b, c);
#else
  f2 r; r[0] = __builtin_fmaf(a[0], b[0], c[0]); r[1] = __builtin_fmaf(a[1], b[1], c[1]); return r;
#endif
}

// ---------------- workspace layout (floats) ----------------
constexpr int OFF_LE    = 0;                    // T*B*K
constexpr int OFF_ALPHA = 1048576;              // T*B*K
constexpr int OFF_EBAR  = 2097152;              // T*B*K
constexpr int OFF_PBUF  = 3145728;              // C*B*64 (P rows; rbuf aliases after fwd scan)
constexpr int OFF_RLOG  = 3670016;              // C*B
constexpr int OFF_AIN   = 3678208;              // C*B*K
constexpr int OFF_SB    = 3743744;              // C*B*K
constexpr int OFF_SBUF  = 3809280;              // S*B*64 = 65536
constexpr int OFF_UBUF  = 3874816;              // S*B*64 = 65536
constexpr int OFF_ULOG  = 3940352;              // S*B = 1024
constexpr int OFF_SAIN  = 3941376;              // S*B*K = 8192
constexpr int OFF_BENT  = 3949568;              // S*B*K = 8192
constexpr int OFF_PRM   = 3957760;              // params; total ~15.9 MB

// params region (relative to OFF_PRM), float-indexed
constexpr int P_LINV0 = 0;       // 8*16*16
constexpr int P_LINVT = 2048;    // 8*16*16
constexpr int P_LD0   = 4096;    // 8
constexpr int P_LDT   = 4104;    // 8
constexpr int P_LOGPI = 4112;    // 8
constexpr int P_QEXP  = 4120;    // 64
constexpr int P_QTEXP = 4184;    // 64

// output layout (floats)
constexpr int OUT_PAIRED = B_*T_*K_;                       // 1048576
constexpr int OUT_LOGZ   = OUT_PAIRED + B_*(T_-1)*K_*K_;   // 9433088

// ---------------- DPP helpers (aligned groups of 8 lanes) ----------------
template<int CTRL>
__device__ __forceinline__ float dppmov(float x) {
  int xi = __float_as_int(x);
  int r = __builtin_amdgcn_update_dpp(xi, xi, CTRL, 0xF, 0xF, true);
  return __int_as_float(r);
}
// 0xB1=xor1, 0x4E=xor2, 0x141=row_half_mirror=xor7 (within 8)
__device__ __forceinline__ void allg8(float v, float w[8]) {
  w[0] = v;
  w[1] = dppmov<0xB1>(v);
  w[2] = dppmov<0x4E>(v);
  w[3] = dppmov<0x4E>(w[1]);
  w[7] = dppmov<0x141>(v);
  w[6] = dppmov<0xB1>(w[7]);
  w[5] = dppmov<0x4E>(w[7]);
  w[4] = dppmov<0x4E>(w[6]);
}
template<int V> __device__ __forceinline__ float xorg8(float x);
template<> __device__ __forceinline__ float xorg8<0>(float x) { return x; }
template<> __device__ __forceinline__ float xorg8<1>(float x) { return dppmov<0xB1>(x); }
template<> __device__ __forceinline__ float xorg8<2>(float x) { return dppmov<0x4E>(x); }
template<> __device__ __forceinline__ float xorg8<3>(float x) { return dppmov<0x4E>(dppmov<0xB1>(x)); }
template<> __device__ __forceinline__ float xorg8<4>(float x) { return dppmov<0x4E>(dppmov<0xB1>(dppmov<0x141>(x))); }
template<> __device__ __forceinline__ float xorg8<5>(float x) { return dppmov<0x4E>(dppmov<0x141>(x)); }
template<> __device__ __forceinline__ float xorg8<6>(float x) { return dppmov<0xB1>(dppmov<0x141>(x)); }
template<> __device__ __forceinline__ float xorg8<7>(float x) { return dppmov<0x141>(x); }

__device__ __forceinline__ float bfly_sum8(float x) {
  x += dppmov<0xB1>(x); x += dppmov<0x4E>(x); x += dppmov<0x141>(x); return x;
}
__device__ __forceinline__ float bfly_max8(float x) {
  x = fmaxf(x, dppmov<0xB1>(x)); x = fmaxf(x, dppmov<0x4E>(x)); x = fmaxf(x, dppmov<0x141>(x)); return x;
}
__device__ __forceinline__ float rcpnr(float x) {
  float r0 = __builtin_amdgcn_rcpf(x);
  return r0 * __builtin_fmaf(-x, r0, 2.0f);
}
// column-xor layout cl[u]=M[j^u][j] -> row-xor layout rv[v]=M[j][j^v]
__device__ __forceinline__ void col2row(const float cl[8], float rv[8]) {
  rv[0] = cl[0];
  rv[1] = xorg8<1>(cl[1]);
  rv[2] = xorg8<2>(cl[2]);
  rv[3] = xorg8<3>(cl[3]);
  rv[4] = xorg8<4>(cl[4]);
  rv[5] = xorg8<5>(cl[5]);
  rv[6] = xorg8<6>(cl[6]);
  rv[7] = xorg8<7>(cl[7]);
}
// o = A x M, all in row-xor layout: o[v] = sum_u a[u] * M[i^u][i^v]
__device__ __forceinline__ void mmul8(const float a[8], const float m[8], float o[8]) {
  float m8[8][8];
  #pragma unroll
  for (int w = 0; w < 8; w++) allg8(m[w], m8[w]);
  #pragma unroll
  for (int v = 0; v < 8; v++) {
    float acc = 0.f;
    #pragma unroll
    for (int u = 0; u < 8; u++) acc = __builtin_fmaf(a[u], m8[u^v][u], acc);
    o[v] = acc;
  }
}
__device__ __forceinline__ float maxnorm8(float m[8]) {   // returns mx, scales m by 1/mx
  float mx = m[0];
  #pragma unroll
  for (int u = 1; u < 8; u++) mx = fmaxf(mx, m[u]);
  mx = bfly_max8(mx);
  float r = rcpnr(mx);
  #pragma unroll
  for (int u = 0; u < 8; u++) m[u] *= r;
  return mx;
}
__device__ __forceinline__ void load_rows(const float* p, float r[8]) {
  const float4* q = (const float4*)p;
  float4 x0 = q[0], x1 = q[1];
  r[0]=x0.x; r[1]=x0.y; r[2]=x0.z; r[3]=x0.w;
  r[4]=x1.x; r[5]=x1.y; r[6]=x1.z; r[7]=x1.w;
}

// ---------------- kernel 1: Cholesky / softmax params ----------------
__global__ __launch_bounds__(64) void prep_kernel(
    const float* __restrict__ pi, const float* __restrict__ Q,
    const float* __restrict__ init_cov, const float* __restrict__ covs,
    float* __restrict__ prm)
{
  int tid = threadIdx.x;
  int blk = blockIdx.x;
  if (blk < 16) {
    int k = blk & 7;
    const float* C = (blk < 8 ? init_cov : covs) + k*256;
    float* outL  = prm + (blk < 8 ? P_LINV0 : P_LINVT) + k*256;
    float* outld = prm + (blk < 8 ? P_LD0   : P_LDT)   + k;
    __shared__ float S[16][17], L[16][17], X[16][17];
    for (int e = tid; e < 256; e += 64) {
      int r = e >> 4, c = e & 15;
      float s = (r == c) ? 1e-6f : 0.f;
      for (int l = 0; l < 16; l++) s += C[r*16+l] * C[c*16+l];
      S[r][c] = s;
    }
    __syncthreads();
    for (int j = 0; j < 16; j++) {
      if (tid == 0) L[j][j] = sqrtf(S[j][j]);
      __syncthreads();
      if (tid > j && tid < 16) L[tid][j] = S[tid][j] / L[j][j];
      __syncthreads();
      if (tid > j && tid < 16) {
        float ltj = L[tid][j];
        for (int c = j+1; c <= tid; c++) S[tid][c] -= ltj * L[c][j];
      }
      __syncthreads();
    }
    if (tid < 16) {
      int c = tid;
      for (int r = 0; r < 16; r++) {
        float v;
        if (r < c) v = 0.f;
        else {
          v = (r == c) ? 1.f : 0.f;
          for (int s2 = c; s2 < r; s2++) v -= L[r][s2] * X[s2][c];
          v /= L[r][r];
        }
        X[r][c] = v;
      }
    }
    __syncthreads();
    for (int e = tid; e < 256; e += 64) outL[e] = X[e>>4][e&15];
    if (tid == 0) {
      float ld = 0.f;
      for (int j = 0; j < 16; j++) ld += logf(L[j][j]);
      *outld = ld;
    }
  } else {
    if (tid < 8) {
      int row = tid;
      float q[8], mx = -1e30f;
      for (int j = 0; j < 8; j++) { q[j] = Q[row*8+j]; mx = fmaxf(mx, q[j]); }
      float s = 0.f;
      for (int j = 0; j < 8; j++) s += __expf(q[j]-mx);
      float ls = logf(s);
      for (int j = 0; j < 8; j++) {
        float e = __expf(q[j]-mx-ls);
        prm[P_QEXP  + row*8 + j] = e;
        prm[P_QTEXP + j*8 + row] = e;
      }
    } else if (tid == 8) {
      float p[8], mx = -1e30f;
      for (int j = 0; j < 8; j++) { p[j] = pi[j]; mx = fmaxf(mx, p[j]); }
      float s = 0.f;
      for (int j = 0; j < 8; j++) s += __expf(p[j]-mx);
      float ls = logf(s);
      for (int j = 0; j < 8; j++) prm[P_LOGPI+j] = p[j]-mx-ls;
    }
  }
}

// ---------------- kernel 2: emissions (packed fp32), wave=(k,t), lane=b ------
__global__ __launch_bounds__(256) void emisA_kernel(
    const float* __restrict__ z, const float* __restrict__ W1,
    const float* __restrict__ b1, const float* __restrict__ W2,
    const float* __restrict__ b2, const float* __restrict__ init_mean,
    const float* __restrict__ prm, float* __restrict__ lebuf)
{
  int b = threadIdx.x & 63;
  int wid = __builtin_amdgcn_readfirstlane(blockIdx.x * 4 + (threadIdx.x >> 6));
  int k = wid >> 11;          // wave-uniform
  int t = wid & 2047;         // wave-uniform
  float zc[16];
  {
    const float4* p4 = (const float4*)(z + (b*T_ + t)*LD_);
    float4 v0=p4[0], v1=p4[1], v2=p4[2], v3=p4[3];
    zc[0]=v0.x; zc[1]=v0.y; zc[2]=v0.z; zc[3]=v0.w;
    zc[4]=v1.x; zc[5]=v1.y; zc[6]=v1.z; zc[7]=v1.w;
    zc[8]=v2.x; zc[9]=v2.y; zc[10]=v2.z; zc[11]=v2.w;
    zc[12]=v3.x; zc[13]=v3.y; zc[14]=v3.z; zc[15]=v3.w;
  }
  float le;
  if (t == 0) {
    float diff[16];
    #pragma unroll
    for (int l = 0; l < 16; l++) diff[l] = zc[l] - init_mean[k*16+l];
    const float* Li = prm + P_LINV0 + k*256;
    float maha = 0.f;
    #pragma unroll
    for (int d = 0; d < 16; d++) {
      float y = 0.f;
      #pragma unroll
      for (int e = 0; e < 16; e++) y = __builtin_fmaf(Li[d*16+e], diff[e], y);
      maha = __builtin_fmaf(y, y, maha);
    }
    le = -0.5f*maha - prm[P_LD0+k] - 14.70301653f + prm[P_LOGPI+k];
  } else {
    float zp[16];
    {
      const float4* p4 = (const float4*)(z + (b*T_ + t - 1)*LD_);
      float4 v0=p4[0], v1=p4[1], v2=p4[2], v3=p4[3];
      zp[0]=v0.x; zp[1]=v0.y; zp[2]=v0.z; zp[3]=v0.w;
      zp[4]=v1.x; zp[5]=v1.y; zp[6]=v1.z; zp[7]=v1.w;
      zp[8]=v2.x; zp[9]=v2.y; zp[10]=v2.z; zp[11]=v2.w;
      zp[12]=v3.x; zp[13]=v3.y; zp[14]=v3.z; zp[15]=v3.w;
    }
    const f2* W1p = (const f2*)(W1 + k*1024);     // [hh][8]
    const f2* W2p = (const f2*)(W2 + k*1024);     // [d][32]
    const f2* Lip = (const f2*)(prm + P_LINVT + k*256);  // [d][8]
    f2 zp2[8];
    #pragma unroll
    for (int lp = 0; lp < 8; lp++) { f2 v = {zp[2*lp], zp[2*lp+1]}; zp2[lp] = v; }
    float h[64];
    #pragma unroll
    for (int hh = 0; hh < 64; hh++) {
      f2 acc = {b1[k*64+hh], 0.f};
      #pragma unroll
      for (int lp = 0; lp < 8; lp++) acc = efma(W1p[hh*8+lp], zp2[lp], acc);
      float a = acc[0] + acc[1];
      h[hh] = fmaxf(a, 0.f) + __logf(1.f + __expf(-fabsf(a)));
    }
    f2 hv[32];
    #pragma unroll
    for (int hp = 0; hp < 32; hp++) { f2 v = {h[2*hp], h[2*hp+1]}; hv[hp] = v; }
    float diff[16];
    #pragma unroll
    for (int d = 0; d < 16; d++) {
      f2 acc = {b2[k*16+d], 0.f};
      #pragma unroll
      for (int hp = 0; hp < 32; hp++) acc = efma(W2p[d*32+hp], hv[hp], acc);
      diff[d] = zc[d] - (acc[0] + acc[1]);
    }
    f2 dv[8];
    #pragma unroll
    for (int ep = 0; ep < 8; ep++) { f2 v = {diff[2*ep], diff[2*ep+1]}; dv[ep] = v; }
    float maha = 0.f;
    #pragma unroll
    for (int d = 0; d < 16; d++) {
      f2 acc = {0.f, 0.f};
      #pragma unroll
      for (int ep = 0; ep < 8; ep++) acc = efma(Lip[d*8+ep], dv[ep], acc);
      float y = acc[0] + acc[1];
      maha = __builtin_fmaf(y, y, maha);
    }
    le = -0.5f*maha - prm[P_LDT+k] - 14.70301653f;
  }
  lebuf[t*512 + k*64 + b] = le;
}

// ---------------- fwd P1: per-(b,chunk) operator products -> ROW layout ------
__global__ __launch_bounds__(256) void fwdP1_kernel(
    const float* __restrict__ lebuf, const float* __restrict__ prm,
    float* __restrict__ pbuf)
{
  int g = (blockIdx.x*256 + threadIdx.x) >> 3;   // 0..8191
  int j = threadIdx.x & 7;
  int b = g & 63, c = g >> 6;                    // c 0..127
  float qtv[64];
  #pragma unroll
  for (int u = 0; u < 8; u++)
    #pragma unroll
    for (int v = 0; v < 8; v++)
      qtv[u*8+v] = prm[P_QTEXP + (j^u)*8 + (j^v)];
  float lev[16];
  #pragma unroll
  for (int u = 0; u < 16; u++) lev[u] = lebuf[(c*L_+u)*512 + j*64 + b];
  float pl[8];
  int ustart;
  if (c == 0) {
    float m = bfly_max8(lev[0]);
    float e = __expf(lev[0]-m);
    allg8(e, pl);                // P[:,j] = ehat_0 (all columns equal)
    ustart = 1;
  } else {
    #pragma unroll
    for (int u = 0; u < 8; u++) pl[u] = (u == 0) ? 1.f : 0.f;
    ustart = 0;
  }
  for (int s = ustart; s < 16; s++) {
    float m = bfly_max8(lev[s]);
    float e = __expf(lev[s]-m);
    float e8[8]; allg8(e, e8);
    float np[8];
    #pragma unroll
    for (int u = 0; u < 8; u++) {
      float acc = 0.f;
      #pragma unroll
      for (int v = 0; v < 8; v++) acc = __builtin_fmaf(qtv[u*8+v], pl[v], acc);
      np[u] = e8[u] * acc;
    }
    float mx = np[0];
    #pragma unroll
    for (int u = 1; u < 8; u++) mx = fmaxf(mx, np[u]);
    mx = bfly_max8(mx);
    float r = rcpnr(mx);
    #pragma unroll
    for (int u = 0; u < 8; u++) pl[u] = np[u] * r;
  }
  float rv[8]; col2row(pl, rv);
  float4* dst = (float4*)(pbuf + g*64 + j*8);
  dst[0] = make_float4(rv[0], rv[1], rv[2], rv[3]);
  dst[1] = make_float4(rv[4], rv[5], rv[6], rv[7]);
}

// ---------------- fwd P2a: super-chunk products S_s = P_{8s+7}...P_{8s} ------
__global__ __launch_bounds__(256) void fwdP2a_kernel(
    const float* __restrict__ pbuf, float* __restrict__ sbuf)
{
  int g = (blockIdx.x*256 + threadIdx.x) >> 3;   // 0..1023
  int i = threadIdx.x & 7;
  int b = g & 63, s = g >> 6;                    // s 0..15
  float m[8];
  load_rows(pbuf + ((8*s)*64 + b)*64 + i*8, m);
  for (int c = 8*s+1; c <= 8*s+7; c++) {
    float a[8];
    load_rows(pbuf + (c*64 + b)*64 + i*8, a);
    float nm[8];
    mmul8(a, m, nm);
    maxnorm8(nm);
    #pragma unroll
    for (int v = 0; v < 8; v++) m[v] = nm[v];
  }
  float4* dst = (float4*)(sbuf + (s*64 + b)*64 + i*8);
  dst[0] = make_float4(m[0], m[1], m[2], m[3]);
  dst[1] = make_float4(m[4], m[5], m[6], m[7]);
}

// ---------------- fwd P2b: serial over 16 supers -> sain ---------------------
__global__ __launch_bounds__(512) void fwdP2b_kernel(
    const float* __restrict__ sbuf, float* __restrict__ sain)
{
  int lane = threadIdx.x;
  int b = lane >> 3, i = lane & 7;
  const float4* base = (const float4*)sbuf;
  float4 c0 = base[(0*64+b)*16 + i*2], c1 = base[(0*64+b)*16 + i*2 + 1];
  float a = 0.125f;
  for (int s = 0; s < 16; s++) {
    int s2 = (s < 15) ? s+1 : 15;
    float4 n0 = base[(s2*64+b)*16 + i*2], n1 = base[(s2*64+b)*16 + i*2 + 1];
    float aw[8]; allg8(a, aw);
    float sm = ((c0.x*aw[0] + c0.y*aw[1]) + (c0.z*aw[2] + c0.w*aw[3]))
             + ((c1.x*aw[4] + c1.y*aw[5]) + (c1.z*aw[6] + c1.w*aw[7]));
    float tot = bfly_sum8(sm);
    float an = sm * rcpnr(tot);
    if (s < 15) { a = an; sain[(s+1)*512 + b*8 + i] = a; }
    c0 = n0; c1 = n1;
  }
}

// ---------------- fwd P2c: per-super walk -> ain for every chunk -------------
__global__ __launch_bounds__(256) void fwdP2c_kernel(
    const float* __restrict__ pbuf, const float* __restrict__ sain,
    float* __restrict__ ain)
{
  int g = (blockIdx.x*256 + threadIdx.x) >> 3;   // 0..1023
  int i = threadIdx.x & 7;
  int b = g & 63, s = g >> 6;
  float a = (s == 0) ? 0.125f : sain[s*512 + b*8 + i];
  ain[(8*s)*512 + b*8 + i] = a;
  for (int u = 0; u < 7; u++) {
    int c = 8*s + u;
    float r[8];
    load_rows(pbuf + (c*64 + b)*64 + i*8, r);
    float aw[8]; allg8(a, aw);
    float sm = ((r[0]*aw[0] + r[1]*aw[1]) + (r[2]*aw[2] + r[3]*aw[3]))
             + ((r[4]*aw[4] + r[5]*aw[5]) + (r[6]*aw[6] + r[7]*aw[7]));
    float tot = bfly_sum8(sm);
    a = sm * rcpnr(tot);
    ain[(c+1)*512 + b*8 + i] = a;
  }
}

// ---------------- fwd P3 (+ fused bwd chunk products -> ROW layout) ----------
__global__ __launch_bounds__(256) void fwdP3_kernel(
    const float* __restrict__ lebuf, const float* __restrict__ prm,
    const float* __restrict__ ain, float* __restrict__ alpha,
    float* __restrict__ ebar, float* __restrict__ rbuf,
    float* __restrict__ rlog, float* __restrict__ out)
{
  int g = (blockIdx.x*256 + threadIdx.x) >> 3;
  int i = threadIdx.x & 7;
  int b = g & 63, c = g >> 6;
  int off = b*8 + i;
  float q[8];
  #pragma unroll
  for (int u = 0; u < 8; u++) q[u] = prm[P_QTEXP + i*8 + (i^u)];
  float lev[16];
  #pragma unroll
  for (int u = 0; u < 16; u++) lev[u] = lebuf[(c*L_+u)*512 + i*64 + b];
  float* logZ = out + OUT_LOGZ + b*T_;
  float eb_loc[16];
  float a;
  int ustart;
  if (c == 0) {
    float m0 = bfly_max8(lev[0]);
    float e0 = __expf(lev[0]-m0);
    float ct = bfly_sum8(e0);
    float r = rcpnr(ct);
    a = e0 * r;
    alpha[off] = a;
    eb_loc[0] = a;
    ebar[off] = a;
    if (i == 0) logZ[0] = m0 + __logf(ct);
    ustart = 1;
  } else {
    a = ain[c*512 + off];
    ustart = 0;
  }
  for (int u = ustart; u < 16; u++) {
    int t = c*L_ + u;
    float m = bfly_max8(lev[u]);
    float e = __expf(lev[u]-m);
    float w[8]; allg8(a, w);
    float dot = ((q[0]*w[0]+q[1]*w[1]) + (q[2]*w[2]+q[3]*w[3]))
              + ((q[4]*w[4]+q[5]*w[5]) + (q[6]*w[6]+q[7]*w[7]));
    float p = e * dot;
    float ct = bfly_sum8(p);
    float r = rcpnr(ct);
    a = p * r;
    alpha[t*512 + off] = a;
    float eb = e * r;
    eb_loc[u] = eb;
    ebar[t*512 + off] = eb;
    if (i == 0) logZ[t] = m + __logf(ct);
  }
  // fused backward chunk product: R_c = Q E_{cL+1} ... Q E_{cL+15}
  float qv[64];
  #pragma unroll
  for (int u = 0; u < 8; u++)
    #pragma unroll
    for (int v = 0; v < 8; v++)
      qv[u*8+v] = prm[P_QEXP + (i^u)*8 + (i^v)];
  float rl[8];
  #pragma unroll
  for (int u = 0; u < 8; u++) rl[u] = (u == 0) ? 1.f : 0.f;
  float lsc = 0.f;
  #pragma unroll
  for (int s = 15; s >= 1; s--) {
    float e8[8]; allg8(eb_loc[s], e8);
    float nr[8];
    #pragma unroll
    for (int u = 0; u < 8; u++) {
      float acc = 0.f;
      #pragma unroll
      for (int v = 0; v < 8; v++) acc = __builtin_fmaf(qv[u*8+v], e8[v]*rl[v], acc);
      nr[u] = acc;
    }
    float mx = nr[0];
    #pragma unroll
    for (int u = 1; u < 8; u++) mx = fmaxf(mx, nr[u]);
    mx = bfly_max8(mx);
    float r = rcpnr(mx);
    #pragma unroll
    for (int u = 0; u < 8; u++) rl[u] = nr[u] * r;
    lsc += __logf(mx);
  }
  float rv[8]; col2row(rl, rv);
  float4* dst = (float4*)(rbuf + g*64 + i*8);
  dst[0] = make_float4(rv[0], rv[1], rv[2], rv[3]);
  dst[1] = make_float4(rv[4], rv[5], rv[6], rv[7]);
  if (i == 0) rlog[g] = lsc;
}

// ---------------- bwd P2a: super products U_s = G_{8s}...G_{8s+7} ------------
// G_c = Q diag(ebar_{c*16}) R_c ; stored max-normalized with log ulog
__global__ __launch_bounds__(256) void bwdP2a_kernel(
    const float* __restrict__ rbuf, const float* __restrict__ rlog,
    const float* __restrict__ ebar, const float* __restrict__ prm,
    float* __restrict__ ubuf, float* __restrict__ ulog)
{
  int g = (blockIdx.x*256 + threadIdx.x) >> 3;   // 0..1023
  int i = threadIdx.x & 7;
  int b = g & 63, s = g >> 6;
  float qr[8];
  #pragma unroll
  for (int u = 0; u < 8; u++) qr[u] = prm[P_QEXP + i*8 + (i^u)];
  float m[8], lsum;
  {
    int c = 8*s + 7;
    float r[8];
    load_rows(rbuf + (c*64 + b)*64 + i*8, r);
    float e = ebar[(c*L_)*512 + b*8 + i];
    float d[8];
    #pragma unroll
    for (int v = 0; v < 8; v++) d[v] = e * r[v];
    mmul8(qr, d, m);
    lsum = rlog[c*64 + b] + __logf(maxnorm8(m));
  }
  for (int c = 8*s + 6; c >= 8*s; c--) {
    float r[8];
    load_rows(rbuf + (c*64 + b)*64 + i*8, r);
    float e = ebar[(c*L_)*512 + b*8 + i];
    float t[8];
    mmul8(r, m, t);                      // T = R_c x M
    #pragma unroll
    for (int v = 0; v < 8; v++) t[v] *= e;   // diag(e) T
    float nm[8];
    mmul8(qr, t, nm);                    // M' = Q x (diag(e) T)
    lsum += rlog[c*64 + b] + __logf(maxnorm8(nm));
    #pragma unroll
    for (int v = 0; v < 8; v++) m[v] = nm[v];
  }
  float4* dst = (float4*)(ubuf + (s*64 + b)*64 + i*8);
  dst[0] = make_float4(m[0], m[1], m[2], m[3]);
  dst[1] = make_float4(m[4], m[5], m[6], m[7]);
  if (i == 0) ulog[s*64 + b] = lsum;
}

// ---------------- bwd P2b: serial over supers -> bent (beta at super tops) ---
__global__ __launch_bounds__(512) void bwdP2b_kernel(
    const float* __restrict__ ubuf, const float* __restrict__ ulog,
    float* __restrict__ bent)
{
  int lane = threadIdx.x;
  int b = lane >> 3, i = lane & 7;
  bent[15*512 + b*8 + i] = 1.f;
  const float4* base = (const float4*)ubuf;
  float sh = 1.f, sig = 0.f;              // true beta_top = sh * exp(sig)
  float4 c0 = base[(15*64+b)*16 + i*2], c1 = base[(15*64+b)*16 + i*2 + 1];
  float cu = ulog[15*64 + b];
  for (int s = 15; s >= 1; s--) {
    int s2 = (s > 1) ? s-1 : 1;
    float4 n0 = base[(s2*64+b)*16 + i*2], n1 = base[(s2*64+b)*16 + i*2 + 1];
    float nu = ulog[s2*64 + b];
    float sw[8]; allg8(sh, sw);
    float y = ((c0.x*sw[0] + c0.y*sw[1]) + (c0.z*sw[2] + c0.w*sw[3]))
            + ((c1.x*sw[4] + c1.y*sw[5]) + (c1.z*sw[6] + c1.w*sw[7]));
    float mx = bfly_max8(y);
    sh = y * rcpnr(mx);
    sig += cu + __logf(mx);
    bent[(s-1)*512 + b*8 + i] = sh * __expf(sig);
    c0 = n0; c1 = n1; cu = nu;
  }
}

// ---------------- bwd P2c: per-super walk -> sb (beta at chunk bottoms) ------
__global__ __launch_bounds__(256) void bwdP2c_kernel(
    const float* __restrict__ rbuf, const float* __restrict__ rlog,
    const float* __restrict__ ebar, const float* __restrict__ prm,
    const float* __restrict__ bent, float* __restrict__ sb)
{
  int g = (blockIdx.x*256 + threadIdx.x) >> 3;   // 0..1023
  int i = threadIdx.x & 7;
  int b = g & 63, s = g >> 6;
  float qr[8];
  #pragma unroll
  for (int u = 0; u < 8; u++) qr[u] = prm[P_QEXP + i*8 + (i^u)];
  float bt = bent[s*512 + b*8 + i];       // beta at top of super s (actual)
  for (int c = 8*s + 7; c >= 8*s; c--) {
    float r[8];
    load_rows(rbuf + (c*64 + b)*64 + i*8, r);
    float e = ebar[(c*L_)*512 + b*8 + i];
    float rl = rlog[c*64 + b];
    float btw[8]; allg8(bt, btw);
    float y = ((r[0]*btw[0] + r[1]*btw[1]) + (r[2]*btw[2] + r[3]*btw[3]))
            + ((r[4]*btw[4] + r[5]*btw[5]) + (r[6]*btw[6] + r[7]*btw[7]));
    y *= __expf(rl);                      // beta at t = c*16 (actual)
    sb[c*512 + b*8 + i] = y;
    float w[8]; allg8(e*y, w);
    float nb = 0.f;
    #pragma unroll
    for (int v = 0; v < 8; v++) nb = __builtin_fmaf(qr[v], w[v], nb);
    bt = nb;                              // beta at t = c*16-1
  }
}

// ---------------- bwd P3 fused with gamma/paired emission --------------------
__global__ __launch_bounds__(256) void bwdP3_kernel(
    const float* __restrict__ alpha, const float* __restrict__ ebar,
    const float* __restrict__ sb, const float* __restrict__ prm,
    float* __restrict__ out)
{
  int g = (blockIdx.x*256 + threadIdx.x) >> 3;
  int i = threadIdx.x & 7;
  int b = g & 63, c = g >> 6;
  int off = b*8 + i;
  float q[8];
  #pragma unroll
  for (int u = 0; u < 8; u++) q[u] = prm[P_QEXP + i*8 + (i^u)];
  float av[16], ev[16];
  #pragma unroll
  for (int u = 0; u < 16; u++) av[u] = alpha[(c*L_+u)*512 + off];
  #pragma unroll
  for (int u = 1; u < 16; u++) ev[u] = ebar[(c*L_+u)*512 + off];
  float* po = out + OUT_PAIRED + b*((T_-1)*64);
  float* go = out + b*(T_*K_);
  float bb;
  if (c == 127) {
    bb = 1.f;
    go[2047*8 + i] = av[15];             // gamma at t=2047 (beta=1)
  } else {
    float ev16 = ebar[((c+1)*L_)*512 + off];
    float sbv  = sb[(c+1)*512 + off];
    float w[8]; allg8(ev16*sbv, w);
    bb = ((q[0]*w[0]+q[1]*w[1]) + (q[2]*w[2]+q[3]*w[3]))
       + ((q[4]*w[4]+q[5]*w[5]) + (q[6]*w[6]+q[7]*w[7]));
    int t = c*L_ + 15;
    #pragma unroll
    for (int u2 = 0; u2 < 8; u2++)
      po[t*64 + i*8 + (i^u2)] = av[15] * q[u2] * w[u2];
    go[t*8 + i] = av[15] * bb;
  }
  #pragma unroll
  for (int u = 15; u >= 1; u--) {
    float w[8]; allg8(ev[u]*bb, w);
    float nb = ((q[0]*w[0]+q[1]*w[1]) + (q[2]*w[2]+q[3]*w[3]))
             + ((q[4]*w[4]+q[5]*w[5]) + (q[6]*w[6]+q[7]*w[7]));
    int t = c*L_ + u - 1;
    #pragma unroll
    for (int u2 = 0; u2 < 8; u2++)
      po[t*64 + i*8 + (i^u2)] = av[u-1] * q[u2] * w[u2];
    go[t*8 + i] = av[u-1] * nb;
    bb = nb;
  }
}

extern "C" void kernel_launch(void* const* d_in, const int* in_sizes, int n_in,
                              void* d_out, int out_size, void* d_ws, size_t ws_size,
                              hipStream_t stream) {
  const float* z         = (const float*)d_in[0];
  const float* pi        = (const float*)d_in[1];
  const float* Q         = (const float*)d_in[2];
  const float* init_mean = (const float*)d_in[3];
  const float* init_cov  = (const float*)d_in[4];
  const float* covs      = (const float*)d_in[5];
  const float* W1        = (const float*)d_in[6];
  const float* b1        = (const float*)d_in[7];
  const float* W2        = (const float*)d_in[8];
  const float* b2        = (const float*)d_in[9];
  float* out = (float*)d_out;
  float* ws  = (float*)d_ws;

  prep_kernel<<<17, 64, 0, stream>>>(pi, Q, init_cov, covs, ws + OFF_PRM);
  emisA_kernel<<<4096, 256, 0, stream>>>(z, W1, b1, W2, b2, init_mean,
                                         ws + OFF_PRM, ws + OFF_LE);
  fwdP1_kernel<<<256, 256, 0, stream>>>(ws + OFF_LE, ws + OFF_PRM, ws + OFF_PBUF);
  fwdP2a_kernel<<<32, 256, 0, stream>>>(ws + OFF_PBUF, ws + OFF_SBUF);
  fwdP2b_kernel<<<1, 512, 0, stream>>>(ws + OFF_SBUF, ws + OFF_SAIN);
  fwdP2c_kernel<<<32, 256, 0, stream>>>(ws + OFF_PBUF, ws + OFF_SAIN, ws + OFF_AIN);
  fwdP3_kernel<<<256, 256, 0, stream>>>(ws + OFF_LE, ws + OFF_PRM, ws + OFF_AIN,
                                        ws + OFF_ALPHA, ws + OFF_EBAR,
                                        ws + OFF_PBUF, ws + OFF_RLOG, out);
  bwdP2a_kernel<<<32, 256, 0, stream>>>(ws + OFF_PBUF, ws + OFF_RLOG,
                                        ws + OFF_EBAR, ws + OFF_PRM,
                                        ws + OFF_UBUF, ws + OFF_ULOG);
  bwdP2b_kernel<<<1, 512, 0, stream>>>(ws + OFF_UBUF, ws + OFF_ULOG, ws + OFF_BENT);
  bwdP2c_kernel<<<32, 256, 0, stream>>>(ws + OFF_PBUF, ws + OFF_RLOG,
                                        ws + OFF_EBAR, ws + OFF_PRM,
                                        ws + OFF_BENT, ws + OFF_SB);
  bwdP3_kernel<<<256, 256, 0, stream>>>(ws + OFF_ALPHA, ws + OFF_EBAR,
                                        ws + OFF_SB, ws + OFF_PRM, out);
}

// Round 8
// 296.533 us; speedup vs baseline: 2.4862x; 1.0002x over previous
//
#include <hip/hip_runtime.h>

#define B_ 64
#define T_ 2048
#define LD_ 16
#define HD_ 64
#define K_ 8
#define L_ 16
#define C_ 128
#define S_ 16   // supers (8 chunks each)

// ---------------- workspace layout (floats) ----------------
constexpr int OFF_LE    = 0;                    // T*B*K
constexpr int OFF_ALPHA = 1048576;              // T*B*K  (zT aliases ALPHA+EBAR pre-fwdP3)
constexpr int OFF_EBAR  = 2097152;              // T*B*K
constexpr int OFF_ZT    = OFF_ALPHA;            // T*B*16 = 2097152 floats (dead after emisA)
constexpr int OFF_PBUF  = 3145728;              // C*B*64 (P rows; rbuf aliases after fwd scan)
constexpr int OFF_RLOG  = 3670016;              // C*B
constexpr int OFF_AIN   = 3678208;              // C*B*K
constexpr int OFF_SB    = 3743744;              // C*B*K
constexpr int OFF_SBUF  = 3809280;              // S*B*64 = 65536
constexpr int OFF_UBUF  = 3874816;              // S*B*64 = 65536
constexpr int OFF_ULOG  = 3940352;              // S*B = 1024
constexpr int OFF_SAIN  = 3941376;              // S*B*K = 8192
constexpr int OFF_BENT  = 3949568;              // S*B*K = 8192
constexpr int OFF_PRM   = 3957760;              // params; total ~15.9 MB

// params region (relative to OFF_PRM), float-indexed
constexpr int P_LINV0 = 0;       // 8*16*16
constexpr int P_LINVT = 2048;    // 8*16*16
constexpr int P_LD0   = 4096;    // 8
constexpr int P_LDT   = 4104;    // 8
constexpr int P_LOGPI = 4112;    // 8
constexpr int P_QEXP  = 4120;    // 64
constexpr int P_QTEXP = 4184;    // 64

// output layout (floats)
constexpr int OUT_PAIRED = B_*T_*K_;                       // 1048576
constexpr int OUT_LOGZ   = OUT_PAIRED + B_*(T_-1)*K_*K_;   // 9433088

// ---------------- DPP helpers (aligned groups of 8 lanes) ----------------
template<int CTRL>
__device__ __forceinline__ float dppmov(float x) {
  int xi = __float_as_int(x);
  int r = __builtin_amdgcn_update_dpp(xi, xi, CTRL, 0xF, 0xF, true);
  return __int_as_float(r);
}
// 0xB1=xor1, 0x4E=xor2, 0x141=row_half_mirror=xor7 (within 8)
__device__ __forceinline__ void allg8(float v, float w[8]) {
  w[0] = v;
  w[1] = dppmov<0xB1>(v);
  w[2] = dppmov<0x4E>(v);
  w[3] = dppmov<0x4E>(w[1]);
  w[7] = dppmov<0x141>(v);
  w[6] = dppmov<0xB1>(w[7]);
  w[5] = dppmov<0x4E>(w[7]);
  w[4] = dppmov<0x4E>(w[6]);
}
template<int V> __device__ __forceinline__ float xorg8(float x);
template<> __device__ __forceinline__ float xorg8<0>(float x) { return x; }
template<> __device__ __forceinline__ float xorg8<1>(float x) { return dppmov<0xB1>(x); }
template<> __device__ __forceinline__ float xorg8<2>(float x) { return dppmov<0x4E>(x); }
template<> __device__ __forceinline__ float xorg8<3>(float x) { return dppmov<0x4E>(dppmov<0xB1>(x)); }
template<> __device__ __forceinline__ float xorg8<4>(float x) { return dppmov<0x4E>(dppmov<0xB1>(dppmov<0x141>(x))); }
template<> __device__ __forceinline__ float xorg8<5>(float x) { return dppmov<0x4E>(dppmov<0x141>(x)); }
template<> __device__ __forceinline__ float xorg8<6>(float x) { return dppmov<0xB1>(dppmov<0x141>(x)); }
template<> __device__ __forceinline__ float xorg8<7>(float x) { return dppmov<0x141>(x); }

__device__ __forceinline__ float bfly_sum8(float x) {
  x += dppmov<0xB1>(x); x += dppmov<0x4E>(x); x += dppmov<0x141>(x); return x;
}
__device__ __forceinline__ float bfly_max8(float x) {
  x = fmaxf(x, dppmov<0xB1>(x)); x = fmaxf(x, dppmov<0x4E>(x)); x = fmaxf(x, dppmov<0x141>(x)); return x;
}
__device__ __forceinline__ float rcpnr(float x) {
  float r0 = __builtin_amdgcn_rcpf(x);
  return r0 * __builtin_fmaf(-x, r0, 2.0f);
}
// column-xor layout cl[u]=M[j^u][j] -> row-xor layout rv[v]=M[j][j^v]
__device__ __forceinline__ void col2row(const float cl[8], float rv[8]) {
  rv[0] = cl[0];
  rv[1] = xorg8<1>(cl[1]);
  rv[2] = xorg8<2>(cl[2]);
  rv[3] = xorg8<3>(cl[3]);
  rv[4] = xorg8<4>(cl[4]);
  rv[5] = xorg8<5>(cl[5]);
  rv[6] = xorg8<6>(cl[6]);
  rv[7] = xorg8<7>(cl[7]);
}
// o = A x M, all in row-xor layout: o[v] = sum_u a[u] * M[i^u][i^v]
__device__ __forceinline__ void mmul8(const float a[8], const float m[8], float o[8]) {
  float m8[8][8];
  #pragma unroll
  for (int w = 0; w < 8; w++) allg8(m[w], m8[w]);
  #pragma unroll
  for (int v = 0; v < 8; v++) {
    float acc = 0.f;
    #pragma unroll
    for (int u = 0; u < 8; u++) acc = __builtin_fmaf(a[u], m8[u^v][u], acc);
    o[v] = acc;
  }
}
__device__ __forceinline__ float maxnorm8(float m[8]) {   // returns mx, scales m by 1/mx
  float mx = m[0];
  #pragma unroll
  for (int u = 1; u < 8; u++) mx = fmaxf(mx, m[u]);
  mx = bfly_max8(mx);
  float r = rcpnr(mx);
  #pragma unroll
  for (int u = 0; u < 8; u++) m[u] *= r;
  return mx;
}
__device__ __forceinline__ void load_rows(const float* p, float r[8]) {
  const float4* q = (const float4*)p;
  float4 x0 = q[0], x1 = q[1];
  r[0]=x0.x; r[1]=x0.y; r[2]=x0.z; r[3]=x0.w;
  r[4]=x1.x; r[5]=x1.y; r[6]=x1.z; r[7]=x1.w;
}

// ---------------- kernel 1: Cholesky / softmax params ----------------
__global__ __launch_bounds__(64) void prep_kernel(
    const float* __restrict__ pi, const float* __restrict__ Q,
    const float* __restrict__ init_cov, const float* __restrict__ covs,
    float* __restrict__ prm)
{
  int tid = threadIdx.x;
  int blk = blockIdx.x;
  if (blk < 16) {
    int k = blk & 7;
    const float* C = (blk < 8 ? init_cov : covs) + k*256;
    float* outL  = prm + (blk < 8 ? P_LINV0 : P_LINVT) + k*256;
    float* outld = prm + (blk < 8 ? P_LD0   : P_LDT)   + k;
    __shared__ float S[16][17], L[16][17], X[16][17];
    for (int e = tid; e < 256; e += 64) {
      int r = e >> 4, c = e & 15;
      float s = (r == c) ? 1e-6f : 0.f;
      for (int l = 0; l < 16; l++) s += C[r*16+l] * C[c*16+l];
      S[r][c] = s;
    }
    __syncthreads();
    for (int j = 0; j < 16; j++) {
      if (tid == 0) L[j][j] = sqrtf(S[j][j]);
      __syncthreads();
      if (tid > j && tid < 16) L[tid][j] = S[tid][j] / L[j][j];
      __syncthreads();
      if (tid > j && tid < 16) {
        float ltj = L[tid][j];
        for (int c = j+1; c <= tid; c++) S[tid][c] -= ltj * L[c][j];
      }
      __syncthreads();
    }
    if (tid < 16) {
      int c = tid;
      for (int r = 0; r < 16; r++) {
        float v;
        if (r < c) v = 0.f;
        else {
          v = (r == c) ? 1.f : 0.f;
          for (int s2 = c; s2 < r; s2++) v -= L[r][s2] * X[s2][c];
          v /= L[r][r];
        }
        X[r][c] = v;
      }
    }
    __syncthreads();
    for (int e = tid; e < 256; e += 64) outL[e] = X[e>>4][e&15];
    if (tid == 0) {
      float ld = 0.f;
      for (int j = 0; j < 16; j++) ld += logf(L[j][j]);
      *outld = ld;
    }
  } else {
    if (tid < 8) {
      int row = tid;
      float q[8], mx = -1e30f;
      for (int j = 0; j < 8; j++) { q[j] = Q[row*8+j]; mx = fmaxf(mx, q[j]); }
      float s = 0.f;
      for (int j = 0; j < 8; j++) s += __expf(q[j]-mx);
      float ls = logf(s);
      for (int j = 0; j < 8; j++) {
        float e = __expf(q[j]-mx-ls);
        prm[P_QEXP  + row*8 + j] = e;
        prm[P_QTEXP + j*8 + row] = e;
      }
    } else if (tid == 8) {
      float p[8], mx = -1e30f;
      for (int j = 0; j < 8; j++) { p[j] = pi[j]; mx = fmaxf(mx, p[j]); }
      float s = 0.f;
      for (int j = 0; j < 8; j++) s += __expf(p[j]-mx);
      float ls = logf(s);
      for (int j = 0; j < 8; j++) prm[P_LOGPI+j] = p[j]-mx-ls;
    }
  }
}

// ---------------- kernel 1b: z -> time-major zT[t][b][16] --------------------
__global__ __launch_bounds__(256) void ztr_kernel(
    const float* __restrict__ z, float* __restrict__ zt)
{
  int tid = blockIdx.x*256 + threadIdx.x;   // 0..131071
  int t = tid >> 6, b = tid & 63;
  const float4* src = (const float4*)(z + (b*T_ + t)*LD_);
  float4* dst = (float4*)(zt + t*1024 + b*16);
  dst[0] = src[0]; dst[1] = src[1]; dst[2] = src[2]; dst[3] = src[3];
}

// ---------------- kernel 2: emissions (fp32), wave=(k,t), lane=b -------------
__global__ __launch_bounds__(256) void emisA_kernel(
    const float* __restrict__ zt, const float* __restrict__ W1,
    const float* __restrict__ b1, const float* __restrict__ W2,
    const float* __restrict__ b2, const float* __restrict__ init_mean,
    const float* __restrict__ prm, float* __restrict__ lebuf)
{
  int b = threadIdx.x & 63;
  int wid = __builtin_amdgcn_readfirstlane(blockIdx.x * 4 + (threadIdx.x >> 6));
  int k = wid >> 11;          // wave-uniform
  int t = wid & 2047;         // wave-uniform
  float zc[16];
  {
    const float4* p4 = (const float4*)(zt + t*1024 + b*16);   // coalesced
    float4 v0=p4[0], v1=p4[1], v2=p4[2], v3=p4[3];
    zc[0]=v0.x; zc[1]=v0.y; zc[2]=v0.z; zc[3]=v0.w;
    zc[4]=v1.x; zc[5]=v1.y; zc[6]=v1.z; zc[7]=v1.w;
    zc[8]=v2.x; zc[9]=v2.y; zc[10]=v2.z; zc[11]=v2.w;
    zc[12]=v3.x; zc[13]=v3.y; zc[14]=v3.z; zc[15]=v3.w;
  }
  float le;
  if (t == 0) {
    float diff[16];
    #pragma unroll
    for (int l = 0; l < 16; l++) diff[l] = zc[l] - init_mean[k*16+l];
    const float* Li = prm + P_LINV0 + k*256;
    float maha = 0.f;
    #pragma unroll
    for (int d = 0; d < 16; d++) {
      float y = 0.f;
      #pragma unroll
      for (int e = 0; e < 16; e++) y = __builtin_fmaf(Li[d*16+e], diff[e], y);
      maha = __builtin_fmaf(y, y, maha);
    }
    le = -0.5f*maha - prm[P_LD0+k] - 14.70301653f + prm[P_LOGPI+k];
  } else {
    float zp[16];
    {
      const float4* p4 = (const float4*)(zt + (t-1)*1024 + b*16);  // coalesced
      float4 v0=p4[0], v1=p4[1], v2=p4[2], v3=p4[3];
      zp[0]=v0.x; zp[1]=v0.y; zp[2]=v0.z; zp[3]=v0.w;
      zp[4]=v1.x; zp[5]=v1.y; zp[6]=v1.z; zp[7]=v1.w;
      zp[8]=v2.x; zp[9]=v2.y; zp[10]=v2.z; zp[11]=v2.w;
      zp[12]=v3.x; zp[13]=v3.y; zp[14]=v3.z; zp[15]=v3.w;
    }
    float h[64];
    #pragma unroll
    for (int hh = 0; hh < 64; hh++) {
      float a = b1[k*64+hh];
      #pragma unroll
      for (int l = 0; l < 16; l++) a = __builtin_fmaf(W1[k*1024 + hh*16 + l], zp[l], a);
      h[hh] = fmaxf(a, 0.f) + __logf(1.f + __expf(-fabsf(a)));
    }
    float diff[16];
    #pragma unroll
    for (int d = 0; d < 16; d++) {
      float mu = b2[k*16+d];
      #pragma unroll
      for (int hh = 0; hh < 64; hh++) mu = __builtin_fmaf(W2[k*1024 + d*64 + hh], h[hh], mu);
      diff[d] = zc[d] - mu;
    }
    const float* Li = prm + P_LINVT + k*256;
    float maha = 0.f;
    #pragma unroll
    for (int d = 0; d < 16; d++) {
      float y = 0.f;
      #pragma unroll
      for (int e = 0; e < 16; e++) y = __builtin_fmaf(Li[d*16+e], diff[e], y);
      maha = __builtin_fmaf(y, y, maha);
    }
    le = -0.5f*maha - prm[P_LDT+k] - 14.70301653f;
  }
  lebuf[t*512 + k*64 + b] = le;
}

// ---------------- fwd P1: per-(b,chunk) operator products -> ROW layout ------
__global__ __launch_bounds__(256) void fwdP1_kernel(
    const float* __restrict__ lebuf, const float* __restrict__ prm,
    float* __restrict__ pbuf)
{
  int g = (blockIdx.x*256 + threadIdx.x) >> 3;   // 0..8191
  int j = threadIdx.x & 7;
  int b = g & 63, c = g >> 6;                    // c 0..127
  float qtv[64];
  #pragma unroll
  for (int u = 0; u < 8; u++)
    #pragma unroll
    for (int v = 0; v < 8; v++)
      qtv[u*8+v] = prm[P_QTEXP + (j^u)*8 + (j^v)];
  float lev[16];
  #pragma unroll
  for (int u = 0; u < 16; u++) lev[u] = lebuf[(c*L_+u)*512 + j*64 + b];
  float pl[8];
  int ustart;
  if (c == 0) {
    float m = bfly_max8(lev[0]);
    float e = __expf(lev[0]-m);
    allg8(e, pl);                // P[:,j] = ehat_0 (all columns equal)
    ustart = 1;
  } else {
    #pragma unroll
    for (int u = 0; u < 8; u++) pl[u] = (u == 0) ? 1.f : 0.f;
    ustart = 0;
  }
  for (int s = ustart; s < 16; s++) {
    float m = bfly_max8(lev[s]);
    float e = __expf(lev[s]-m);
    float e8[8]; allg8(e, e8);
    float np[8];
    #pragma unroll
    for (int u = 0; u < 8; u++) {
      float acc = 0.f;
      #pragma unroll
      for (int v = 0; v < 8; v++) acc = __builtin_fmaf(qtv[u*8+v], pl[v], acc);
      np[u] = e8[u] * acc;
    }
    float mx = np[0];
    #pragma unroll
    for (int u = 1; u < 8; u++) mx = fmaxf(mx, np[u]);
    mx = bfly_max8(mx);
    float r = rcpnr(mx);
    #pragma unroll
    for (int u = 0; u < 8; u++) pl[u] = np[u] * r;
  }
  float rv[8]; col2row(pl, rv);
  float4* dst = (float4*)(pbuf + g*64 + j*8);
  dst[0] = make_float4(rv[0], rv[1], rv[2], rv[3]);
  dst[1] = make_float4(rv[4], rv[5], rv[6], rv[7]);
}

// ---------------- fwd P2a: super-chunk products S_s = P_{8s+7}...P_{8s} ------
__global__ __launch_bounds__(256) void fwdP2a_kernel(
    const float* __restrict__ pbuf, float* __restrict__ sbuf)
{
  int g = (blockIdx.x*256 + threadIdx.x) >> 3;   // 0..1023
  int i = threadIdx.x & 7;
  int b = g & 63, s = g >> 6;                    // s 0..15
  float m[8];
  load_rows(pbuf + ((8*s)*64 + b)*64 + i*8, m);
  for (int c = 8*s+1; c <= 8*s+7; c++) {
    float a[8];
    load_rows(pbuf + (c*64 + b)*64 + i*8, a);
    float nm[8];
    mmul8(a, m, nm);
    maxnorm8(nm);
    #pragma unroll
    for (int v = 0; v < 8; v++) m[v] = nm[v];
  }
  float4* dst = (float4*)(sbuf + (s*64 + b)*64 + i*8);
  dst[0] = make_float4(m[0], m[1], m[2], m[3]);
  dst[1] = make_float4(m[4], m[5], m[6], m[7]);
}

// ---------------- fwd P2b: serial over 16 supers -> sain ---------------------
__global__ __launch_bounds__(512) void fwdP2b_kernel(
    const float* __restrict__ sbuf, float* __restrict__ sain)
{
  int lane = threadIdx.x;
  int b = lane >> 3, i = lane & 7;
  const float4* base = (const float4*)sbuf;
  float4 c0 = base[(0*64+b)*16 + i*2], c1 = base[(0*64+b)*16 + i*2 + 1];
  float a = 0.125f;
  for (int s = 0; s < 16; s++) {
    int s2 = (s < 15) ? s+1 : 15;
    float4 n0 = base[(s2*64+b)*16 + i*2], n1 = base[(s2*64+b)*16 + i*2 + 1];
    float aw[8]; allg8(a, aw);
    float sm = ((c0.x*aw[0] + c0.y*aw[1]) + (c0.z*aw[2] + c0.w*aw[3]))
             + ((c1.x*aw[4] + c1.y*aw[5]) + (c1.z*aw[6] + c1.w*aw[7]));
    float tot = bfly_sum8(sm);
    float an = sm * rcpnr(tot);
    if (s < 15) { a = an; sain[(s+1)*512 + b*8 + i] = a; }
    c0 = n0; c1 = n1;
  }
}

// ---------------- fwd P2c: per-super walk -> ain for every chunk -------------
__global__ __launch_bounds__(256) void fwdP2c_kernel(
    const float* __restrict__ pbuf, const float* __restrict__ sain,
    float* __restrict__ ain)
{
  int g = (blockIdx.x*256 + threadIdx.x) >> 3;   // 0..1023
  int i = threadIdx.x & 7;
  int b = g & 63, s = g >> 6;
  float a = (s == 0) ? 0.125f : sain[s*512 + b*8 + i];
  ain[(8*s)*512 + b*8 + i] = a;
  for (int u = 0; u < 7; u++) {
    int c = 8*s + u;
    float r[8];
    load_rows(pbuf + (c*64 + b)*64 + i*8, r);
    float aw[8]; allg8(a, aw);
    float sm = ((r[0]*aw[0] + r[1]*aw[1]) + (r[2]*aw[2] + r[3]*aw[3]))
             + ((r[4]*aw[4] + r[5]*aw[5]) + (r[6]*aw[6] + r[7]*aw[7]));
    float tot = bfly_sum8(sm);
    a = sm * rcpnr(tot);
    ain[(c+1)*512 + b*8 + i] = a;
  }
}

// ---------------- fwd P3 (+ fused bwd chunk products -> ROW layout) ----------
__global__ __launch_bounds__(256) void fwdP3_kernel(
    const float* __restrict__ lebuf, const float* __restrict__ prm,
    const float* __restrict__ ain, float* __restrict__ alpha,
    float* __restrict__ ebar, float* __restrict__ rbuf,
    float* __restrict__ rlog, float* __restrict__ out)
{
  int g = (blockIdx.x*256 + threadIdx.x) >> 3;
  int i = threadIdx.x & 7;
  int b = g & 63, c = g >> 6;
  int off = b*8 + i;
  float q[8];
  #pragma unroll
  for (int u = 0; u < 8; u++) q[u] = prm[P_QTEXP + i*8 + (i^u)];
  float lev[16];
  #pragma unroll
  for (int u = 0; u < 16; u++) lev[u] = lebuf[(c*L_+u)*512 + i*64 + b];
  float* logZ = out + OUT_LOGZ + b*T_;
  float eb_loc[16];
  float a;
  int ustart;
  if (c == 0) {
    float m0 = bfly_max8(lev[0]);
    float e0 = __expf(lev[0]-m0);
    float ct = bfly_sum8(e0);
    float r = rcpnr(ct);
    a = e0 * r;
    alpha[off] = a;
    eb_loc[0] = a;
    ebar[off] = a;
    if (i == 0) logZ[0] = m0 + __logf(ct);
    ustart = 1;
  } else {
    a = ain[c*512 + off];
    ustart = 0;
  }
  for (int u = ustart; u < 16; u++) {
    int t = c*L_ + u;
    float m = bfly_max8(lev[u]);
    float e = __expf(lev[u]-m);
    float w[8]; allg8(a, w);
    float dot = ((q[0]*w[0]+q[1]*w[1]) + (q[2]*w[2]+q[3]*w[3]))
              + ((q[4]*w[4]+q[5]*w[5]) + (q[6]*w[6]+q[7]*w[7]));
    float p = e * dot;
    float ct = bfly_sum8(p);
    float r = rcpnr(ct);
    a = p * r;
    alpha[t*512 + off] = a;
    float eb = e * r;
    eb_loc[u] = eb;
    ebar[t*512 + off] = eb;
    if (i == 0) logZ[t] = m + __logf(ct);
  }
  // fused backward chunk product: R_c = Q E_{cL+1} ... Q E_{cL+15}
  float qv[64];
  #pragma unroll
  for (int u = 0; u < 8; u++)
    #pragma unroll
    for (int v = 0; v < 8; v++)
      qv[u*8+v] = prm[P_QEXP + (i^u)*8 + (i^v)];
  float rl[8];
  #pragma unroll
  for (int u = 0; u < 8; u++) rl[u] = (u == 0) ? 1.f : 0.f;
  float lsc = 0.f;
  #pragma unroll
  for (int s = 15; s >= 1; s--) {
    float e8[8]; allg8(eb_loc[s], e8);
    float nr[8];
    #pragma unroll
    for (int u = 0; u < 8; u++) {
      float acc = 0.f;
      #pragma unroll
      for (int v = 0; v < 8; v++) acc = __builtin_fmaf(qv[u*8+v], e8[v]*rl[v], acc);
      nr[u] = acc;
    }
    float mx = nr[0];
    #pragma unroll
    for (int u = 1; u < 8; u++) mx = fmaxf(mx, nr[u]);
    mx = bfly_max8(mx);
    float r = rcpnr(mx);
    #pragma unroll
    for (int u = 0; u < 8; u++) rl[u] = nr[u] * r;
    lsc += __logf(mx);
  }
  float rv[8]; col2row(rl, rv);
  float4* dst = (float4*)(rbuf + g*64 + i*8);
  dst[0] = make_float4(rv[0], rv[1], rv[2], rv[3]);
  dst[1] = make_float4(rv[4], rv[5], rv[6], rv[7]);
  if (i == 0) rlog[g] = lsc;
}

// ---------------- bwd P2a: super products U_s = G_{8s}...G_{8s+7} ------------
// G_c = Q diag(ebar_{c*16}) R_c ; stored max-normalized with log ulog
__global__ __launch_bounds__(256) void bwdP2a_kernel(
    const float* __restrict__ rbuf, const float* __restrict__ rlog,
    const float* __restrict__ ebar, const float* __restrict__ prm,
    float* __restrict__ ubuf, float* __restrict__ ulog)
{
  int g = (blockIdx.x*256 + threadIdx.x) >> 3;   // 0..1023
  int i = threadIdx.x & 7;
  int b = g & 63, s = g >> 6;
  float qr[8];
  #pragma unroll
  for (int u = 0; u < 8; u++) qr[u] = prm[P_QEXP + i*8 + (i^u)];
  float m[8], lsum;
  {
    int c = 8*s + 7;
    float r[8];
    load_rows(rbuf + (c*64 + b)*64 + i*8, r);
    float e = ebar[(c*L_)*512 + b*8 + i];
    float d[8];
    #pragma unroll
    for (int v = 0; v < 8; v++) d[v] = e * r[v];
    mmul8(qr, d, m);
    lsum = rlog[c*64 + b] + __logf(maxnorm8(m));
  }
  for (int c = 8*s + 6; c >= 8*s; c--) {
    float r[8];
    load_rows(rbuf + (c*64 + b)*64 + i*8, r);
    float e = ebar[(c*L_)*512 + b*8 + i];
    float t[8];
    mmul8(r, m, t);                      // T = R_c x M
    #pragma unroll
    for (int v = 0; v < 8; v++) t[v] *= e;   // diag(e) T
    float nm[8];
    mmul8(qr, t, nm);                    // M' = Q x (diag(e) T)
    lsum += rlog[c*64 + b] + __logf(maxnorm8(nm));
    #pragma unroll
    for (int v = 0; v < 8; v++) m[v] = nm[v];
  }
  float4* dst = (float4*)(ubuf + (s*64 + b)*64 + i*8);
  dst[0] = make_float4(m[0], m[1], m[2], m[3]);
  dst[1] = make_float4(m[4], m[5], m[6], m[7]);
  if (i == 0) ulog[s*64 + b] = lsum;
}

// ---------------- bwd P2b: serial over supers -> bent (beta at super tops) ---
__global__ __launch_bounds__(512) void bwdP2b_kernel(
    const float* __restrict__ ubuf, const float* __restrict__ ulog,
    float* __restrict__ bent)
{
  int lane = threadIdx.x;
  int b = lane >> 3, i = lane & 7;
  bent[15*512 + b*8 + i] = 1.f;
  const float4* base = (const float4*)ubuf;
  float sh = 1.f, sig = 0.f;              // true beta_top = sh * exp(sig)
  float4 c0 = base[(15*64+b)*16 + i*2], c1 = base[(15*64+b)*16 + i*2 + 1];
  float cu = ulog[15*64 + b];
  for (int s = 15; s >= 1; s--) {
    int s2 = (s > 1) ? s-1 : 1;
    float4 n0 = base[(s2*64+b)*16 + i*2], n1 = base[(s2*64+b)*16 + i*2 + 1];
    float nu = ulog[s2*64 + b];
    float sw[8]; allg8(sh, sw);
    float y = ((c0.x*sw[0] + c0.y*sw[1]) + (c0.z*sw[2] + c0.w*sw[3]))
            + ((c1.x*sw[4] + c1.y*sw[5]) + (c1.z*sw[6] + c1.w*sw[7]));
    float mx = bfly_max8(y);
    sh = y * rcpnr(mx);
    sig += cu + __logf(mx);
    bent[(s-1)*512 + b*8 + i] = sh * __expf(sig);
    c0 = n0; c1 = n1; cu = nu;
  }
}

// ---------------- bwd P2c: per-super walk -> sb (beta at chunk bottoms) ------
__global__ __launch_bounds__(256) void bwdP2c_kernel(
    const float* __restrict__ rbuf, const float* __restrict__ rlog,
    const float* __restrict__ ebar, const float* __restrict__ prm,
    const float* __restrict__ bent, float* __restrict__ sb)
{
  int g = (blockIdx.x*256 + threadIdx.x) >> 3;   // 0..1023
  int i = threadIdx.x & 7;
  int b = g & 63, s = g >> 6;
  float qr[8];
  #pragma unroll
  for (int u = 0; u < 8; u++) qr[u] = prm[P_QEXP + i*8 + (i^u)];
  float bt = bent[s*512 + b*8 + i];       // beta at top of super s (actual)
  for (int c = 8*s + 7; c >= 8*s; c--) {
    float r[8];
    load_rows(rbuf + (c*64 + b)*64 + i*8, r);
    float e = ebar[(c*L_)*512 + b*8 + i];
    float rl = rlog[c*64 + b];
    float btw[8]; allg8(bt, btw);
    float y = ((r[0]*btw[0] + r[1]*btw[1]) + (r[2]*btw[2] + r[3]*btw[3]))
            + ((r[4]*btw[4] + r[5]*btw[5]) + (r[6]*btw[6] + r[7]*btw[7]));
    y *= __expf(rl);                      // beta at t = c*16 (actual)
    sb[c*512 + b*8 + i] = y;
    float w[8]; allg8(e*y, w);
    float nb = 0.f;
    #pragma unroll
    for (int v = 0; v < 8; v++) nb = __builtin_fmaf(qr[v], w[v], nb);
    bt = nb;                              // beta at t = c*16-1
  }
}

// ---------------- bwd P3 fused with gamma/paired emission --------------------
__global__ __launch_bounds__(256) void bwdP3_kernel(
    const float* __restrict__ alpha, const float* __restrict__ ebar,
    const float* __restrict__ sb, const float* __restrict__ prm,
    float* __restrict__ out)
{
  int g = (blockIdx.x*256 + threadIdx.x) >> 3;
  int i = threadIdx.x & 7;
  int b = g & 63, c = g >> 6;
  int off = b*8 + i;
  float q[8];
  #pragma unroll
  for (int u = 0; u < 8; u++) q[u] = prm[P_QEXP + i*8 + (i^u)];
  float av[16], ev[16];
  #pragma unroll
  for (int u = 0; u < 16; u++) av[u] = alpha[(c*L_+u)*512 + off];
  #pragma unroll
  for (int u = 1; u < 16; u++) ev[u] = ebar[(c*L_+u)*512 + off];
  float* po = out + OUT_PAIRED + b*((T_-1)*64);
  float* go = out + b*(T_*K_);
  float bb;
  if (c == 127) {
    bb = 1.f;
    go[2047*8 + i] = av[15];             // gamma at t=2047 (beta=1)
  } else {
    float ev16 = ebar[((c+1)*L_)*512 + off];
    float sbv  = sb[(c+1)*512 + off];
    float w[8]; allg8(ev16*sbv, w);
    bb = ((q[0]*w[0]+q[1]*w[1]) + (q[2]*w[2]+q[3]*w[3]))
       + ((q[4]*w[4]+q[5]*w[5]) + (q[6]*w[6]+q[7]*w[7]));
    int t = c*L_ + 15;
    #pragma unroll
    for (int u2 = 0; u2 < 8; u2++)
      po[t*64 + i*8 + (i^u2)] = av[15] * q[u2] * w[u2];
    go[t*8 + i] = av[15] * bb;
  }
  #pragma unroll
  for (int u = 15; u >= 1; u--) {
    float w[8]; allg8(ev[u]*bb, w);
    float nb = ((q[0]*w[0]+q[1]*w[1]) + (q[2]*w[2]+q[3]*w[3]))
             + ((q[4]*w[4]+q[5]*w[5]) + (q[6]*w[6]+q[7]*w[7]));
    int t = c*L_ + u - 1;
    #pragma unroll
    for (int u2 = 0; u2 < 8; u2++)
      po[t*64 + i*8 + (i^u2)] = av[u-1] * q[u2] * w[u2];
    go[t*8 + i] = av[u-1] * nb;
    bb = nb;
  }
}

extern "C" void kernel_launch(void* const* d_in, const int* in_sizes, int n_in,
                              void* d_out, int out_size, void* d_ws, size_t ws_size,
                              hipStream_t stream) {
  const float* z         = (const float*)d_in[0];
  const float* pi        = (const float*)d_in[1];
  const float* Q         = (const float*)d_in[2];
  const float* init_mean = (const float*)d_in[3];
  const float* init_cov  = (const float*)d_in[4];
  const float* covs      = (const float*)d_in[5];
  const float* W1        = (const float*)d_in[6];
  const float* b1        = (const float*)d_in[7];
  const float* W2        = (const float*)d_in[8];
  const float* b2        = (const float*)d_in[9];
  float* out = (float*)d_out;
  float* ws  = (float*)d_ws;

  prep_kernel<<<17, 64, 0, stream>>>(pi, Q, init_cov, covs, ws + OFF_PRM);
  ztr_kernel<<<512, 256, 0, stream>>>(z, ws + OFF_ZT);
  emisA_kernel<<<4096, 256, 0, stream>>>(ws + OFF_ZT, W1, b1, W2, b2, init_mean,
                                         ws + OFF_PRM, ws + OFF_LE);
  fwdP1_kernel<<<256, 256, 0, stream>>>(ws + OFF_LE, ws + OFF_PRM, ws + OFF_PBUF);
  fwdP2a_kernel<<<32, 256, 0, stream>>>(ws + OFF_PBUF, ws + OFF_SBUF);
  fwdP2b_kernel<<<1, 512, 0, stream>>>(ws + OFF_SBUF, ws + OFF_SAIN);
  fwdP2c_kernel<<<32, 256, 0, stream>>>(ws + OFF_PBUF, ws + OFF_SAIN, ws + OFF_AIN);
  fwdP3_kernel<<<256, 256, 0, stream>>>(ws + OFF_LE, ws + OFF_PRM, ws + OFF_AIN,
                                        ws + OFF_ALPHA, ws + OFF_EBAR,
                                        ws + OFF_PBUF, ws + OFF_RLOG, out);
  bwdP2a_kernel<<<32, 256, 0, stream>>>(ws + OFF_PBUF, ws + OFF_RLOG,
                                        ws + OFF_EBAR, ws + OFF_PRM,
                                        ws + OFF_UBUF, ws + OFF_ULOG);
  bwdP2b_kernel<<<1, 512, 0, stream>>>(ws + OFF_UBUF, ws + OFF_ULOG, ws + OFF_BENT);
  bwdP2c_kernel<<<32, 256, 0, stream>>>(ws + OFF_PBUF, ws + OFF_RLOG,
                                        ws + OFF_EBAR, ws + OFF_PRM,
                                        ws + OFF_BENT, ws + OFF_SB);
  bwdP3_kernel<<<256, 256, 0, stream>>>(ws + OFF_ALPHA, ws + OFF_EBAR,
                                        ws + OFF_SB, ws + OFF_PRM, out);
}